// Round 2
// baseline (1343.677 us; speedup 1.0000x reference)
//
#include <hip/hip_runtime.h>
#include <hip/hip_bf16.h>

// DF-HGNN fused pipeline v2: bf16 MFMA everywhere, H pre-transposed to bf16.
// N=20000, E=4096, IN=512, DET=256, HID=256, HALF=128, OUT=2.

typedef __bf16 bf16_t;
typedef __attribute__((ext_vector_type(8))) __bf16 bf16x8;
typedef __attribute__((ext_vector_type(4))) __bf16 bf16x4;
typedef __attribute__((ext_vector_type(4))) float f32x4;

#define NN 20000
#define NE 4096
#define NNP 20032           // 313*64 node-padded extent
#define NSTEPS 626          // NNP/32
#define AT_S 24             // K-split for H^T @ Y
#define OUT_S 4             // e-split for H @ He

__device__ __forceinline__ f32x4 mfma16(bf16x8 a, bf16x8 b, f32x4 c) {
  return __builtin_amdgcn_mfma_f32_16x16x32_bf16(a, b, c, 0, 0, 0);
}

// ---------------- fused stats + bf16 transpose: Dv, De, Ht[e][n] ----------------
// grid (64 e-blocks, 157 n-blocks), tile 128n x 64e staged in LDS.
__global__ __launch_bounds__(256) void stats_cvt_kern(const float* __restrict__ H,
                                                      const float* __restrict__ w,
                                                      float* __restrict__ Dv,
                                                      float* __restrict__ De,
                                                      bf16_t* __restrict__ Ht) {
  __shared__ bf16_t tile[128 * 72];   // stride 72 bf16 = 144B (16B aligned)
  int t = threadIdx.x;
  long e0 = (long)blockIdx.x * 64;
  long n0 = (long)blockIdx.y * 128;
  int r = t >> 1, ch = t & 1;          // 128 rows, 2 thr/row x 32 cols
  long row = n0 + r;
  float dvp = 0.f;
  bf16_t* dstl = tile + r * 72 + ch * 32;
  if (row < NN) {
    const float* hp = H + row * NE + e0 + ch * 32;
    const float* wp = w + e0 + ch * 32;
    #pragma unroll
    for (int q = 0; q < 4; ++q) {
      f32x4 u0 = *(const f32x4*)(hp + q * 8);
      f32x4 u1 = *(const f32x4*)(hp + q * 8 + 4);
      f32x4 w0 = *(const f32x4*)(wp + q * 8);
      f32x4 w1 = *(const f32x4*)(wp + q * 8 + 4);
      bf16x8 b;
      #pragma unroll
      for (int j = 0; j < 4; ++j) { b[j] = (__bf16)u0[j]; b[4 + j] = (__bf16)u1[j]; }
      *(bf16x8*)(dstl + q * 8) = b;
      dvp += u0[0]*w0[0] + u0[1]*w0[1] + u0[2]*w0[2] + u0[3]*w0[3]
           + u1[0]*w1[0] + u1[1]*w1[1] + u1[2]*w1[2] + u1[3]*w1[3];
    }
  } else {
    bf16x8 zz;
    #pragma unroll
    for (int j = 0; j < 8; ++j) zz[j] = (__bf16)0.f;
    #pragma unroll
    for (int q = 0; q < 4; ++q) *(bf16x8*)(dstl + q * 8) = zz;
  }
  dvp += __shfl_xor(dvp, 1);
  if (ch == 0 && row < NN) atomicAdd(&Dv[row], dvp);
  __syncthreads();
  // De column sums: col-pair c2, 16 rows per thread (conflict-free b32 reads)
  {
    int c2 = t & 31, rg = t >> 5;
    float s0 = 0.f, s1 = 0.f;
    #pragma unroll
    for (int j = 0; j < 16; ++j) {
      unsigned u = *(const unsigned*)(tile + (rg * 16 + j) * 72 + c2 * 2);
      s0 += __uint_as_float(u << 16);
      s1 += __uint_as_float(u & 0xffff0000u);
    }
    atomicAdd(&De[e0 + c2 * 2], s0);
    atomicAdd(&De[e0 + c2 * 2 + 1], s1);
  }
  // Ht transpose write: lane -> e, wave -> 32-n chunk (conflict-free LDS reads)
  {
    int e_l = t & 63, ng = t >> 6;
    long nco = n0 + ng * 32;
    if (nco < NNP) {
      bf16x8 v0, v1, v2, v3;
      #pragma unroll
      for (int j = 0; j < 8; ++j) v0[j] = tile[(ng * 32 + j) * 72 + e_l];
      #pragma unroll
      for (int j = 0; j < 8; ++j) v1[j] = tile[(ng * 32 + 8 + j) * 72 + e_l];
      #pragma unroll
      for (int j = 0; j < 8; ++j) v2[j] = tile[(ng * 32 + 16 + j) * 72 + e_l];
      #pragma unroll
      for (int j = 0; j < 8; ++j) v3[j] = tile[(ng * 32 + 24 + j) * 72 + e_l];
      bf16_t* op = Ht + (e0 + e_l) * (long)NNP + nco;
      *(bf16x8*)(op)      = v0;
      *(bf16x8*)(op + 8)  = v1;
      *(bf16x8*)(op + 16) = v2;
      *(bf16x8*)(op + 24) = v3;
    }
  }
}

__global__ void finalize_kern(const float* __restrict__ Dv, const float* __restrict__ De,
                              const float* __restrict__ w,
                              float* __restrict__ isd, float* __restrict__ es) {
  int t = blockIdx.x * 256 + threadIdx.x;
  if (t < NN) isd[t] = rsqrtf(fmaxf(Dv[t], 1e-6f));
  if (t < NE) es[t] = w[t] / fmaxf(De[t], 1e-6f);
}

// -------------------------------------------- weight transpose+cast (tiny)
__global__ void cvtw_kern(const float* __restrict__ psi, const float* __restrict__ phi,
                          const float* __restrict__ g1,  const float* __restrict__ g2,
                          const float* __restrict__ th1, const float* __restrict__ th2,
                          bf16_t* dpsi, bf16_t* dphi, bf16_t* dg1, bf16_t* dg2,
                          bf16_t* dth1, bf16_t* dth2) {
  int t = blockIdx.x * 256 + threadIdx.x;
  if (t < 65536) {                       // psi [512][128] -> [128][512]
    int nc = t >> 9, k = t & 511; dpsi[t] = (__bf16)psi[k * 128 + nc];
  } else if (t < 98304) {                // phi [256][128] -> [128][256]
    int i = t - 65536; int nc = i >> 8, k = i & 255; dphi[i] = (__bf16)phi[k * 128 + nc];
  } else if (t < 163840) {               // g1 [256][256] -> [256][256]
    int i = t - 98304; int nc = i >> 8, k = i & 255; dg1[i] = (__bf16)g1[k * 256 + nc];
  } else if (t < 196608) {               // g2 [256][128] -> [128][256]
    int i = t - 163840; int nc = i >> 8, k = i & 255; dg2[i] = (__bf16)g2[k * 128 + nc];
  } else if (t < 229376) {               // th1 [128][256] -> [256][128]
    int i = t - 196608; int nc = i >> 7, k = i & 127; dth1[i] = (__bf16)th1[k * 256 + nc];
  } else if (t < 294912) {               // th2 [256][256] -> [256][256]
    int i = t - 229376; int nc = i >> 8, k = i & 255; dth2[i] = (__bf16)th2[k * 256 + nc];
  }
}

// --------------------------------------------------- node-feature GEMMs
// C[n][f] = A[n][:K] @ Bt[f][:K]^T. Block: 32 rows x 128 cols, 4 waves (2x2).
enum { EPI_CAT = 0, EPI_RELU = 1, EPI_GATE = 2, EPI_Y = 3 };

template<bool AF32, int EPI>
__global__ __launch_bounds__(256) void gemm_node_kern(
    const void* __restrict__ Av, int lda, const bf16_t* __restrict__ Bt, int K,
    const float* __restrict__ bias, float* __restrict__ gate_out,
    bf16_t* __restrict__ dst, int ldc, const bf16_t* __restrict__ cat,
    const float* __restrict__ isd) {
  int tid = threadIdx.x, l = tid & 63, wv = tid >> 6;
  int lr = l & 15, lq = l >> 4;
  int mo = blockIdx.x * 32 + (wv >> 1) * 16;
  int no = blockIdx.y * 128 + (wv & 1) * 64;
  f32x4 acc[4] = {};
  for (int k0 = 0; k0 < K; k0 += 32) {
    int row = mo + lr;
    bf16x8 a;
    if (row < NN) {
      if constexpr (AF32) {
        const float* ap = (const float*)Av + (long)row * lda + k0 + lq * 8;
        f32x4 u0 = *(const f32x4*)ap, u1 = *(const f32x4*)(ap + 4);
        #pragma unroll
        for (int j = 0; j < 4; ++j) { a[j] = (__bf16)u0[j]; a[j + 4] = (__bf16)u1[j]; }
      } else {
        a = *(const bf16x8*)((const bf16_t*)Av + (long)row * lda + k0 + lq * 8);
      }
    } else {
      #pragma unroll
      for (int j = 0; j < 8; ++j) a[j] = (__bf16)0.f;
    }
    #pragma unroll
    for (int ni = 0; ni < 4; ++ni) {
      bf16x8 b = *(const bf16x8*)(Bt + (long)(no + ni * 16 + lr) * K + k0 + lq * 8);
      acc[ni] = mfma16(a, b, acc[ni]);
    }
  }
  #pragma unroll
  for (int ni = 0; ni < 4; ++ni) {
    int colf = no + ni * 16 + lr;
    int rb = mo + lq * 4;
    f32x4 v = acc[ni];
    if constexpr (EPI == EPI_CAT) {
      float bs = bias[colf];
      for (int r = 0; r < 4; ++r) { int n = rb + r;
        if (n < NN) dst[(long)n * ldc + colf] = (__bf16)(v[r] + bs); }
    } else if constexpr (EPI == EPI_RELU) {
      float bs = bias[colf];
      for (int r = 0; r < 4; ++r) { int n = rb + r;
        if (n < NN) { float xx = v[r] + bs; dst[(long)n * ldc + colf] = (__bf16)(xx > 0.f ? xx : 0.f); } }
    } else if constexpr (EPI == EPI_GATE) {
      float bs = bias[colf];
      for (int r = 0; r < 4; ++r) {
        int n = rb + r;
        if (n < NN) {
          float g = 1.f / (1.f + __expf(-(v[r] + bs)));
          gate_out[(long)n * 128 + colf] = g;
          float px = (float)cat[(long)n * 256 + colf];
          float pz = (float)cat[(long)n * 256 + 128 + colf];
          dst[(long)n * 128 + colf] = (__bf16)(g * pz + (1.f - g) * px);
        }
      }
    } else {  // EPI_Y: Yt[f][n] = C * isd[n], zero-filled for n in [NN, NNP)
      bf16x4 pk;
      for (int r = 0; r < 4; ++r) {
        int nr = rb + r;
        float sc = (nr < NN) ? isd[nr] : 0.f;
        pk[r] = (__bf16)(v[r] * sc);
      }
      *(bf16x4*)(dst + (long)colf * NNP + rb) = pk;
    }
  }
}

// --------------------------------------------- He partials: part[s][f][e]
// He[e][f] = sum_n Ht[e][n]*Yt[f][n]. No LDS: both operands K-contiguous.
__global__ __launch_bounds__(256) void at_gemm_kern(const bf16_t* __restrict__ Ht,
                                                    const bf16_t* __restrict__ Yt,
                                                    bf16_t* __restrict__ part) {
  int t = threadIdx.x, l = t & 63, wv = t >> 6;
  int lr = l & 15, lq = l >> 4;
  int ew = blockIdx.x * 128 + wv * 32;
  int s0 = (blockIdx.y * NSTEPS) / AT_S;
  int s1 = ((blockIdx.y + 1) * NSTEPS) / AT_S;
  f32x4 acc[2][16] = {};
  const bf16_t* ap0 = Ht + (long)(ew + lr) * NNP + lq * 8;
  const bf16_t* ap1 = Ht + (long)(ew + 16 + lr) * NNP + lq * 8;
  const bf16_t* bp  = Yt + (long)lr * NNP + lq * 8;
  for (int s = s0; s < s1; ++s) {
    int nb = s * 32;
    bf16x8 a0 = *(const bf16x8*)(ap0 + nb);
    bf16x8 a1 = *(const bf16x8*)(ap1 + nb);
    #pragma unroll
    for (int ni = 0; ni < 16; ++ni) {
      bf16x8 b = *(const bf16x8*)(bp + (long)ni * 16 * NNP + nb);
      acc[0][ni] = mfma16(a0, b, acc[0][ni]);
      acc[1][ni] = mfma16(a1, b, acc[1][ni]);
    }
  }
  bf16_t* pp = part + (long)blockIdx.y * 256 * NE;
  #pragma unroll
  for (int mi = 0; mi < 2; ++mi)
    #pragma unroll
    for (int ni = 0; ni < 16; ++ni) {
      int f = ni * 16 + lr;
      int e = ew + mi * 16 + lq * 4;
      f32x4 v = acc[mi][ni];
      bf16x4 pk;
      for (int r = 0; r < 4; ++r) pk[r] = (__bf16)v[r];
      *(bf16x4*)(pp + (long)f * NE + e) = pk;
    }
}

// He_t[f][e] = es[e] * sum_s part[s][f][e]
__global__ void reduce_he(const bf16_t* __restrict__ part, const float* __restrict__ es,
                          bf16_t* __restrict__ Het) {
  int t = blockIdx.x * 256 + threadIdx.x;  // over 256*4096
  int e = t & (NE - 1);
  float s = 0.f;
  #pragma unroll
  for (int i = 0; i < AT_S; ++i) s += (float)part[(long)i * 256 * NE + t];
  Het[t] = (__bf16)(s * es[e]);
}

// ----------------- opart[s][n][f] partials of (H @ He): C[f][n] per block
// Block: 64 n x 256 f, e-range NE/OUT_S. B-side (H n-rows) staged via LDS
// transpose from Ht; A-side (Het f-rows) direct L2 loads.
__global__ __launch_bounds__(256) void out_gemm_kern(const bf16_t* __restrict__ Het,
                                                     const bf16_t* __restrict__ Ht,
                                                     bf16_t* __restrict__ opart) {
  __shared__ bf16_t lb[64 * 40];          // [n][e] tile, stride 40 bf16 (80B)
  int t = threadIdx.x, l = t & 63, wv = t >> 6;
  int lr = l & 15, lq = l >> 4;
  long nblk = (long)blockIdx.x * 64;
  int ebase = blockIdx.y * (NE / OUT_S);
  int er2 = t >> 4, nc = t & 15;
  f32x4 acc[16] = {};
  for (int s = 0; s < (NE / OUT_S) / 32; ++s) {
    int e0 = ebase + s * 32;
    __syncthreads();
    { // stage Ht[e0..e0+32)[nblk..nblk+64) transposed into lb[n][e]
      const bf16_t* r0 = Ht + (long)(e0 + 2 * er2) * NNP + nblk + nc * 4;
      bf16x4 va = *(const bf16x4*)r0;
      bf16x4 vb = *(const bf16x4*)(r0 + NNP);
      #pragma unroll
      for (int j = 0; j < 4; ++j) {
        unsigned lo = (unsigned)__builtin_bit_cast(unsigned short, (__bf16)va[j]);
        unsigned hi = (unsigned)__builtin_bit_cast(unsigned short, (__bf16)vb[j]);
        *(unsigned*)(lb + (nc * 4 + j) * 40 + er2 * 2) = lo | (hi << 16);
      }
    }
    __syncthreads();
    bf16x8 b = *(const bf16x8*)(lb + (wv * 16 + lr) * 40 + lq * 8);
    #pragma unroll
    for (int ni = 0; ni < 16; ++ni) {
      bf16x8 a = *(const bf16x8*)(Het + (long)(ni * 16 + lr) * NE + e0 + lq * 8);
      acc[ni] = mfma16(a, b, acc[ni]);
    }
  }
  long n = nblk + wv * 16 + lr;
  bf16_t* pp = opart + (long)blockIdx.y * NNP * 256;
  #pragma unroll
  for (int ni = 0; ni < 16; ++ni) {
    int fb = ni * 16 + lq * 4;
    f32x4 v = acc[ni];
    bf16x4 pk;
    for (int r = 0; r < 4; ++r) pk[r] = (__bf16)v[r];
    *(bf16x4*)(pp + n * 256 + fb) = pk;
  }
}

// ------- h[n][f] = relu(isd[n]*sum_s opart + bias); optionally fused logits
template<int LOGITS>
__global__ __launch_bounds__(256) void reduce_out_kern(const bf16_t* __restrict__ opart,
    const float* __restrict__ isd, const float* __restrict__ bias,
    bf16_t* __restrict__ h, const float* __restrict__ ow, const float* __restrict__ ob,
    float* __restrict__ out) {
  int t = threadIdx.x;
  long n = (long)blockIdx.x * 8 + (t >> 5);
  int fo = (t & 31) * 8;
  float s[8] = {0.f, 0.f, 0.f, 0.f, 0.f, 0.f, 0.f, 0.f};
  #pragma unroll
  for (int si = 0; si < OUT_S; ++si) {
    bf16x8 v = *(const bf16x8*)(opart + (long)si * NNP * 256 + n * 256 + fo);
    #pragma unroll
    for (int j = 0; j < 8; ++j) s[j] += (float)v[j];
  }
  float sd = isd[n];
  bf16x8 hv;
  float a0 = 0.f, a1 = 0.f;
  #pragma unroll
  for (int j = 0; j < 8; ++j) {
    float vv = s[j] * sd + bias[fo + j];
    vv = vv > 0.f ? vv : 0.f;
    hv[j] = (__bf16)vv;
    if (LOGITS) {
      a0 += vv * ow[(fo + j) * 2];
      a1 += vv * ow[(fo + j) * 2 + 1];
    }
  }
  *(bf16x8*)(h + n * 256 + fo) = hv;
  if (LOGITS) {
    #pragma unroll
    for (int m = 1; m < 32; m <<= 1) { a0 += __shfl_xor(a0, m); a1 += __shfl_xor(a1, m); }
    if ((t & 31) == 0) { out[n * 2] = a0 + ob[0]; out[n * 2 + 1] = a1 + ob[1]; }
  }
}

// ============================================================== launcher
extern "C" void kernel_launch(void* const* d_in, const int* in_sizes, int n_in,
                              void* d_out, int out_size, void* d_ws, size_t ws_size,
                              hipStream_t stream) {
  const float* x    = (const float*)d_in[0];
  const float* z    = (const float*)d_in[1];
  const float* H    = (const float*)d_in[2];
  const float* w    = (const float*)d_in[3];
  const float* psi_w = (const float*)d_in[4];
  const float* psi_b = (const float*)d_in[5];
  const float* phi_w = (const float*)d_in[6];
  const float* phi_b = (const float*)d_in[7];
  const float* g1_w  = (const float*)d_in[8];
  const float* g1_b  = (const float*)d_in[9];
  const float* g2_w  = (const float*)d_in[10];
  const float* g2_b  = (const float*)d_in[11];
  const float* th1   = (const float*)d_in[12];
  const float* b1    = (const float*)d_in[13];
  const float* th2   = (const float*)d_in[14];
  const float* b2    = (const float*)d_in[15];
  const float* out_w = (const float*)d_in[16];
  const float* out_b = (const float*)d_in[17];

  float* logits_out = (float*)d_out;                 // [20000][2]
  float* gate_out   = logits_out + (size_t)NN * 2;   // [20000][128]

  char* p = (char*)d_ws;
  auto alloc = [&](size_t bytes) { char* r = p; p += (bytes + 255) & ~(size_t)255; return r; };
  float* Dv   = (float*)alloc((size_t)NN * 4);
  float* De   = (float*)alloc((size_t)NE * 4);
  float* isd  = (float*)alloc((size_t)NN * 4);
  float* es   = (float*)alloc((size_t)NE * 4);
  bf16_t* cat   = (bf16_t*)alloc((size_t)NN * 256 * 2);
  bf16_t* hid1  = (bf16_t*)alloc((size_t)NN * 256 * 2);
  bf16_t* fusedb= (bf16_t*)alloc((size_t)NN * 128 * 2);
  bf16_t* Yt    = (bf16_t*)alloc((size_t)256 * NNP * 2);
  bf16_t* Het   = (bf16_t*)alloc((size_t)256 * NE * 2);
  bf16_t* h     = (bf16_t*)alloc((size_t)NNP * 256 * 2);
  bf16_t* pbuf  = (bf16_t*)alloc((size_t)AT_S * 256 * NE * 2);  // part / opart union
  bf16_t* Ht    = (bf16_t*)alloc((size_t)NE * NNP * 2);
  bf16_t* psi_wt = (bf16_t*)alloc(65536 * 2);
  bf16_t* phi_wt = (bf16_t*)alloc(32768 * 2);
  bf16_t* g1_wt  = (bf16_t*)alloc(65536 * 2);
  bf16_t* g2_wt  = (bf16_t*)alloc(32768 * 2);
  bf16_t* th1_wt = (bf16_t*)alloc(32768 * 2);
  bf16_t* th2_wt = (bf16_t*)alloc(65536 * 2);

  // zero degree accumulators (Dv..es contiguous region start)
  hipMemsetAsync(Dv, 0, ((char*)isd - (char*)Dv), stream);

  cvtw_kern<<<1152, 256, 0, stream>>>(psi_w, phi_w, g1_w, g2_w, th1, th2,
                                      psi_wt, phi_wt, g1_wt, g2_wt, th1_wt, th2_wt);
  stats_cvt_kern<<<dim3(64, 157), 256, 0, stream>>>(H, w, Dv, De, Ht);
  finalize_kern<<<79, 256, 0, stream>>>(Dv, De, w, isd, es);

  // front-end MLP chain
  gemm_node_kern<true,  EPI_CAT ><<<dim3(626, 1), 256, 0, stream>>>(x, 512, psi_wt, 512, psi_b, nullptr, cat,       256, nullptr, nullptr);
  gemm_node_kern<true,  EPI_CAT ><<<dim3(626, 1), 256, 0, stream>>>(z, 256, phi_wt, 256, phi_b, nullptr, cat + 128, 256, nullptr, nullptr);
  gemm_node_kern<false, EPI_RELU><<<dim3(626, 2), 256, 0, stream>>>(cat, 256, g1_wt, 256, g1_b, nullptr, hid1, 256, nullptr, nullptr);
  gemm_node_kern<false, EPI_GATE><<<dim3(626, 1), 256, 0, stream>>>(hid1, 256, g2_wt, 256, g2_b, gate_out, fusedb, 128, cat, nullptr);

  // hconv 1
  gemm_node_kern<false, EPI_Y><<<dim3(626, 2), 256, 0, stream>>>(fusedb, 128, th1_wt, 128, nullptr, nullptr, Yt, 0, nullptr, isd);
  at_gemm_kern<<<dim3(32, AT_S), 256, 0, stream>>>(Ht, Yt, pbuf);
  reduce_he<<<4096, 256, 0, stream>>>(pbuf, es, Het);
  out_gemm_kern<<<dim3(313, OUT_S), 256, 0, stream>>>(Het, Ht, pbuf);
  reduce_out_kern<0><<<2500, 256, 0, stream>>>(pbuf, isd, b1, h, nullptr, nullptr, nullptr);

  // hconv 2
  gemm_node_kern<false, EPI_Y><<<dim3(626, 2), 256, 0, stream>>>(h, 256, th2_wt, 256, nullptr, nullptr, Yt, 0, nullptr, isd);
  at_gemm_kern<<<dim3(32, AT_S), 256, 0, stream>>>(Ht, Yt, pbuf);
  reduce_he<<<4096, 256, 0, stream>>>(pbuf, es, Het);
  out_gemm_kern<<<dim3(313, OUT_S), 256, 0, stream>>>(Het, Ht, pbuf);
  reduce_out_kern<1><<<2500, 256, 0, stream>>>(pbuf, isd, b2, h, out_w, out_b, logits_out);

  (void)in_sizes; (void)n_in; (void)out_size; (void)ws_size;
}

// Round 3
// 1283.513 us; speedup vs baseline: 1.0469x; 1.0469x over previous
//
#include <hip/hip_runtime.h>
#include <hip/hip_bf16.h>

// DF-HGNN fused pipeline v3: single bf16 copy of H (row-major Hb, zero-padded
// to 20480 rows). out_gemm = pure direct-load MFMA (1 block/CU, balanced);
// at_gemm stages the H-transpose tile through LDS with conflict-free packing.
// N=20000, E=4096, IN=512, DET=256, HID=256, HALF=128, OUT=2.

typedef __bf16 bf16_t;
typedef __attribute__((ext_vector_type(8))) __bf16 bf16x8;
typedef __attribute__((ext_vector_type(4))) __bf16 bf16x4;
typedef __attribute__((ext_vector_type(4))) float f32x4;

#define NN 20000
#define NE 4096
#define NNP 20480           // 256*80 = 640*32 padded node extent (zero rows >= NN)
#define NSTEPS 640          // NNP/32
#define AT_S 24             // n-split for H^T @ Y (32 e-blocks x 24 = 768 = 3/CU)

__device__ __forceinline__ f32x4 mfma16(bf16x8 a, bf16x8 b, f32x4 c) {
  return __builtin_amdgcn_mfma_f32_16x16x32_bf16(a, b, c, 0, 0, 0);
}

// ---------------- fused stats + bf16 cast: Dv, De, Hb[n][e] ----------------
// grid (64 e-blocks, 160 n-blocks), tile 128n x 64e; Hb written straight from
// registers (coalesced); LDS tile only for the De column reduction.
__global__ __launch_bounds__(256) void stats_cvt_kern(const float* __restrict__ H,
                                                      const float* __restrict__ w,
                                                      float* __restrict__ Dv,
                                                      float* __restrict__ De,
                                                      bf16_t* __restrict__ Hb) {
  __shared__ bf16_t tile[128 * 72];   // stride 72 bf16 = 144B
  int t = threadIdx.x;
  long e0 = (long)blockIdx.x * 64;
  long n0 = (long)blockIdx.y * 128;
  int r = t >> 1, ch = t & 1;          // 128 rows, 2 thr/row x 32 cols
  long row = n0 + r;
  float dvp = 0.f;
  bf16_t* dstl = tile + r * 72 + ch * 32;
  bf16x8 loc[4];
  if (row < NN) {
    const float* hp = H + row * NE + e0 + ch * 32;
    const float* wp = w + e0 + ch * 32;
    #pragma unroll
    for (int q = 0; q < 4; ++q) {
      f32x4 u0 = *(const f32x4*)(hp + q * 8);
      f32x4 u1 = *(const f32x4*)(hp + q * 8 + 4);
      f32x4 w0 = *(const f32x4*)(wp + q * 8);
      f32x4 w1 = *(const f32x4*)(wp + q * 8 + 4);
      bf16x8 b;
      #pragma unroll
      for (int j = 0; j < 4; ++j) { b[j] = (__bf16)u0[j]; b[4 + j] = (__bf16)u1[j]; }
      loc[q] = b;
      dvp += u0[0]*w0[0] + u0[1]*w0[1] + u0[2]*w0[2] + u0[3]*w0[3]
           + u1[0]*w1[0] + u1[1]*w1[1] + u1[2]*w1[2] + u1[3]*w1[3];
    }
  } else {
    bf16x8 zz;
    #pragma unroll
    for (int j = 0; j < 8; ++j) zz[j] = (__bf16)0.f;
    #pragma unroll
    for (int q = 0; q < 4; ++q) loc[q] = zz;
  }
  #pragma unroll
  for (int q = 0; q < 4; ++q) *(bf16x8*)(dstl + q * 8) = loc[q];
  { // Hb row-major write, fully coalesced (row < NNP always)
    bf16_t* hb = Hb + row * NE + e0 + ch * 32;
    #pragma unroll
    for (int q = 0; q < 4; ++q) *(bf16x8*)(hb + q * 8) = loc[q];
  }
  dvp += __shfl_xor(dvp, 1);
  if (ch == 0 && row < NN) atomicAdd(&Dv[row], dvp);
  __syncthreads();
  // De column sums: col-pair c2, 16 rows per thread (2-way max, free)
  {
    int c2 = t & 31, rg = t >> 5;
    float s0 = 0.f, s1 = 0.f;
    #pragma unroll
    for (int j = 0; j < 16; ++j) {
      unsigned u = *(const unsigned*)(tile + (rg * 16 + j) * 72 + c2 * 2);
      s0 += __uint_as_float(u << 16);
      s1 += __uint_as_float(u & 0xffff0000u);
    }
    atomicAdd(&De[e0 + c2 * 2], s0);
    atomicAdd(&De[e0 + c2 * 2 + 1], s1);
  }
}

__global__ void finalize_kern(const float* __restrict__ Dv, const float* __restrict__ De,
                              const float* __restrict__ w,
                              float* __restrict__ isd, float* __restrict__ es) {
  int t = blockIdx.x * 256 + threadIdx.x;
  if (t < NN) isd[t] = rsqrtf(fmaxf(Dv[t], 1e-6f));
  if (t < NE) es[t] = w[t] / fmaxf(De[t], 1e-6f);
}

// -------------------------------------------- weight transpose+cast (tiny)
__global__ void cvtw_kern(const float* __restrict__ psi, const float* __restrict__ phi,
                          const float* __restrict__ g1,  const float* __restrict__ g2,
                          const float* __restrict__ th1, const float* __restrict__ th2,
                          bf16_t* dpsi, bf16_t* dphi, bf16_t* dg1, bf16_t* dg2,
                          bf16_t* dth1, bf16_t* dth2) {
  int t = blockIdx.x * 256 + threadIdx.x;
  if (t < 65536) {                       // psi [512][128] -> [128][512]
    int nc = t >> 9, k = t & 511; dpsi[t] = (__bf16)psi[k * 128 + nc];
  } else if (t < 98304) {                // phi [256][128] -> [128][256]
    int i = t - 65536; int nc = i >> 8, k = i & 255; dphi[i] = (__bf16)phi[k * 128 + nc];
  } else if (t < 163840) {               // g1 [256][256] -> [256][256]
    int i = t - 98304; int nc = i >> 8, k = i & 255; dg1[i] = (__bf16)g1[k * 256 + nc];
  } else if (t < 196608) {               // g2 [256][128] -> [128][256]
    int i = t - 163840; int nc = i >> 8, k = i & 255; dg2[i] = (__bf16)g2[k * 128 + nc];
  } else if (t < 229376) {               // th1 [128][256] -> [256][128]
    int i = t - 196608; int nc = i >> 7, k = i & 127; dth1[i] = (__bf16)th1[k * 256 + nc];
  } else if (t < 294912) {               // th2 [256][256] -> [256][256]
    int i = t - 229376; int nc = i >> 8, k = i & 255; dth2[i] = (__bf16)th2[k * 256 + nc];
  }
}

// --------------------------------------------------- node-feature GEMMs
// C[n][f] = A[n][:K] @ Bt[f][:K]^T. Block: 32 rows x 128 cols, 4 waves (2x2).
enum { EPI_CAT = 0, EPI_RELU = 1, EPI_GATE = 2, EPI_Y = 3 };

template<bool AF32, int EPI>
__global__ __launch_bounds__(256) void gemm_node_kern(
    const void* __restrict__ Av, int lda, const bf16_t* __restrict__ Bt, int K,
    const float* __restrict__ bias, float* __restrict__ gate_out,
    bf16_t* __restrict__ dst, int ldc, const bf16_t* __restrict__ cat,
    const float* __restrict__ isd) {
  int tid = threadIdx.x, l = tid & 63, wv = tid >> 6;
  int lr = l & 15, lq = l >> 4;
  int mo = blockIdx.x * 32 + (wv >> 1) * 16;
  int no = blockIdx.y * 128 + (wv & 1) * 64;
  f32x4 acc[4] = {};
  for (int k0 = 0; k0 < K; k0 += 32) {
    int row = mo + lr;
    bf16x8 a;
    if (row < NN) {
      if constexpr (AF32) {
        const float* ap = (const float*)Av + (long)row * lda + k0 + lq * 8;
        f32x4 u0 = *(const f32x4*)ap, u1 = *(const f32x4*)(ap + 4);
        #pragma unroll
        for (int j = 0; j < 4; ++j) { a[j] = (__bf16)u0[j]; a[j + 4] = (__bf16)u1[j]; }
      } else {
        a = *(const bf16x8*)((const bf16_t*)Av + (long)row * lda + k0 + lq * 8);
      }
    } else {
      #pragma unroll
      for (int j = 0; j < 8; ++j) a[j] = (__bf16)0.f;
    }
    #pragma unroll
    for (int ni = 0; ni < 4; ++ni) {
      bf16x8 b = *(const bf16x8*)(Bt + (long)(no + ni * 16 + lr) * K + k0 + lq * 8);
      acc[ni] = mfma16(a, b, acc[ni]);
    }
  }
  #pragma unroll
  for (int ni = 0; ni < 4; ++ni) {
    int colf = no + ni * 16 + lr;
    int rb = mo + lq * 4;
    f32x4 v = acc[ni];
    if constexpr (EPI == EPI_CAT) {
      float bs = bias[colf];
      for (int r = 0; r < 4; ++r) { int n = rb + r;
        if (n < NN) dst[(long)n * ldc + colf] = (__bf16)(v[r] + bs); }
    } else if constexpr (EPI == EPI_RELU) {
      float bs = bias[colf];
      for (int r = 0; r < 4; ++r) { int n = rb + r;
        if (n < NN) { float xx = v[r] + bs; dst[(long)n * ldc + colf] = (__bf16)(xx > 0.f ? xx : 0.f); } }
    } else if constexpr (EPI == EPI_GATE) {
      float bs = bias[colf];
      for (int r = 0; r < 4; ++r) {
        int n = rb + r;
        if (n < NN) {
          float g = 1.f / (1.f + __expf(-(v[r] + bs)));
          gate_out[(long)n * 128 + colf] = g;
          float px = (float)cat[(long)n * 256 + colf];
          float pz = (float)cat[(long)n * 256 + 128 + colf];
          dst[(long)n * 128 + colf] = (__bf16)(g * pz + (1.f - g) * px);
        }
      }
    } else {  // EPI_Y: Yt[f][n] = C * isd[n], zero for n in [NN, NNP)
      bf16x4 pk;
      for (int r = 0; r < 4; ++r) {
        int nr = rb + r;
        float sc = (nr < NN) ? isd[nr] : 0.f;
        pk[r] = (__bf16)(v[r] * sc);
      }
      *(bf16x4*)(dst + (long)colf * NNP + rb) = pk;
    }
  }
}

// --------------------------------------------- He partials: part[s][f][e]
// He[e][f] = sum_n Hb[n][e]*Yt[f][n]. A-side transposed through LDS:
// paired-row u32-packed writes with j-rotation (~2-way), stride-40 rows.
__global__ __launch_bounds__(256) void at_gemm_kern(const bf16_t* __restrict__ Hb,
                                                    const bf16_t* __restrict__ Yt,
                                                    bf16_t* __restrict__ part) {
  __shared__ bf16_t T[128 * 40];       // [e_local][n_local], 80B rows (16B-aligned)
  int t = threadIdx.x, l = t & 63, wv = t >> 6;
  int lr = l & 15, lq = l >> 4;
  int e0 = blockIdx.x * 128;
  int s0 = (blockIdx.y * NSTEPS) / AT_S;
  int s1 = ((blockIdx.y + 1) * NSTEPS) / AT_S;
  int n2 = t & 15, chunk = t >> 4;     // staging: row-pair (2n2,2n2+1), 8-e chunk
  f32x4 acc[2][16] = {};
  const bf16_t* bp = Yt + (long)lr * NNP + lq * 8;
  for (int s = s0; s < s1; ++s) {
    int n0 = s * 32;
    const bf16_t* src = Hb + (long)(n0 + 2 * n2) * NE + e0 + chunk * 8;
    bf16x8 ra = *(const bf16x8*)src;
    bf16x8 rb = *(const bf16x8*)(src + NE);
    __syncthreads();
    #pragma unroll
    for (int j = 0; j < 8; ++j) {
      int jj = (j + chunk) & 7;        // rotate to spread banks across chunks
      int el = chunk * 8 + jj;
      unsigned lo = (unsigned)__builtin_bit_cast(unsigned short, (__bf16)ra[jj]);
      unsigned hi = (unsigned)__builtin_bit_cast(unsigned short, (__bf16)rb[jj]);
      *(unsigned*)(T + el * 40 + n2 * 2) = lo | (hi << 16);
    }
    __syncthreads();
    bf16x8 a0 = *(const bf16x8*)(T + (wv * 32 + lr) * 40 + lq * 8);
    bf16x8 a1 = *(const bf16x8*)(T + (wv * 32 + 16 + lr) * 40 + lq * 8);
    #pragma unroll
    for (int ni = 0; ni < 16; ++ni) {
      bf16x8 b = *(const bf16x8*)(bp + (long)ni * 16 * NNP + n0);
      acc[0][ni] = mfma16(a0, b, acc[0][ni]);
      acc[1][ni] = mfma16(a1, b, acc[1][ni]);
    }
  }
  bf16_t* pp = part + (long)blockIdx.y * 256 * NE;
  #pragma unroll
  for (int mi = 0; mi < 2; ++mi)
    #pragma unroll
    for (int ni = 0; ni < 16; ++ni) {
      int f = ni * 16 + lr;
      int e = e0 + wv * 32 + mi * 16 + lq * 4;
      f32x4 v = acc[mi][ni];
      bf16x4 pk;
      for (int r = 0; r < 4; ++r) pk[r] = (__bf16)v[r];
      *(bf16x4*)(pp + (long)f * NE + e) = pk;
    }
}

// He_t[f][e] = es[e] * sum_s part[s][f][e]
__global__ void reduce_he(const bf16_t* __restrict__ part, const float* __restrict__ es,
                          bf16_t* __restrict__ Het) {
  int t = blockIdx.x * 256 + threadIdx.x;  // over 256*4096
  int e = t & (NE - 1);
  float s = 0.f;
  #pragma unroll
  for (int i = 0; i < AT_S; ++i) s += (float)part[(long)i * 256 * NE + t];
  Het[t] = (__bf16)(s * es[e]);
}

// -------- h[n][f] = relu(isd[n]*(Hb[n]@Het^T) + bias) ---------------------
// grid exactly 256 blocks (1/CU), 8 waves, wave tile 80n x 32f. No LDS.
// A (Hb rows) streamed from HBM; B (Het rows) L2-resident. Reg double-buffer.
__global__ __launch_bounds__(512) void out_gemm_kern(const bf16_t* __restrict__ Het,
                                                     const bf16_t* __restrict__ Hb,
                                                     const float* __restrict__ isd,
                                                     const float* __restrict__ bias,
                                                     bf16_t* __restrict__ h) {
  int t = threadIdx.x, l = t & 63, wv = t >> 6;
  int lr = l & 15, lq = l >> 4;
  long r0 = (long)blockIdx.x * 80;
  int fo = wv * 32;
  f32x4 acc[5][2] = {};
  const bf16_t* ap = Hb + (r0 + lr) * (long)NE + lq * 8;
  const bf16_t* bp = Het + (long)(fo + lr) * NE + lq * 8;
  bf16x8 a[5], b[2];
  #pragma unroll
  for (int mi = 0; mi < 5; ++mi) a[mi] = *(const bf16x8*)(ap + (long)mi * 16 * NE);
  b[0] = *(const bf16x8*)(bp);
  b[1] = *(const bf16x8*)(bp + (long)16 * NE);
  for (int k0 = 32; k0 < NE; k0 += 32) {
    bf16x8 an[5], bn[2];
    #pragma unroll
    for (int mi = 0; mi < 5; ++mi) an[mi] = *(const bf16x8*)(ap + (long)mi * 16 * NE + k0);
    bn[0] = *(const bf16x8*)(bp + k0);
    bn[1] = *(const bf16x8*)(bp + (long)16 * NE + k0);
    #pragma unroll
    for (int mi = 0; mi < 5; ++mi) {
      acc[mi][0] = mfma16(a[mi], b[0], acc[mi][0]);
      acc[mi][1] = mfma16(a[mi], b[1], acc[mi][1]);
    }
    #pragma unroll
    for (int mi = 0; mi < 5; ++mi) a[mi] = an[mi];
    b[0] = bn[0]; b[1] = bn[1];
  }
  #pragma unroll
  for (int mi = 0; mi < 5; ++mi) {
    acc[mi][0] = mfma16(a[mi], b[0], acc[mi][0]);
    acc[mi][1] = mfma16(a[mi], b[1], acc[mi][1]);
  }
  #pragma unroll
  for (int mi = 0; mi < 5; ++mi) {
    long nb = r0 + mi * 16 + lq * 4;
    #pragma unroll
    for (int ni = 0; ni < 2; ++ni) {
      int f = fo + ni * 16 + lr;
      float bs = bias[f];
      #pragma unroll
      for (int r = 0; r < 4; ++r) {
        long n = nb + r;
        if (n < NN) {
          float vv = acc[mi][ni][r] * isd[n] + bs;
          h[n * 256 + f] = (__bf16)(vv > 0.f ? vv : 0.f);
        }
      }
    }
  }
}

// ------------------------------------------- logits[n][2] = h[n]@out_w + b
__global__ __launch_bounds__(256) void logits_kern(const bf16_t* __restrict__ h,
                                                   const float* __restrict__ ow,
                                                   const float* __restrict__ ob,
                                                   float* __restrict__ out) {
  __shared__ float lw[512];
  int t = threadIdx.x;
  lw[t * 2] = ow[t * 2];
  lw[t * 2 + 1] = ow[t * 2 + 1];
  __syncthreads();
  int n = blockIdx.x * 256 + t;
  if (n >= NN) return;
  float a0 = ob[0], a1 = ob[1];
  const bf16x8* hp = (const bf16x8*)(h + (long)n * 256);
  for (int c = 0; c < 32; ++c) {
    bf16x8 v = hp[c];
    #pragma unroll
    for (int j = 0; j < 8; ++j) {
      float f = (float)v[j];
      a0 += f * lw[(c * 8 + j) * 2];
      a1 += f * lw[(c * 8 + j) * 2 + 1];
    }
  }
  out[n * 2] = a0;
  out[n * 2 + 1] = a1;
}

// ============================================================== launcher
extern "C" void kernel_launch(void* const* d_in, const int* in_sizes, int n_in,
                              void* d_out, int out_size, void* d_ws, size_t ws_size,
                              hipStream_t stream) {
  const float* x    = (const float*)d_in[0];
  const float* z    = (const float*)d_in[1];
  const float* H    = (const float*)d_in[2];
  const float* w    = (const float*)d_in[3];
  const float* psi_w = (const float*)d_in[4];
  const float* psi_b = (const float*)d_in[5];
  const float* phi_w = (const float*)d_in[6];
  const float* phi_b = (const float*)d_in[7];
  const float* g1_w  = (const float*)d_in[8];
  const float* g1_b  = (const float*)d_in[9];
  const float* g2_w  = (const float*)d_in[10];
  const float* g2_b  = (const float*)d_in[11];
  const float* th1   = (const float*)d_in[12];
  const float* b1    = (const float*)d_in[13];
  const float* th2   = (const float*)d_in[14];
  const float* b2    = (const float*)d_in[15];
  const float* out_w = (const float*)d_in[16];
  const float* out_b = (const float*)d_in[17];

  float* logits_out = (float*)d_out;                 // [20000][2]
  float* gate_out   = logits_out + (size_t)NN * 2;   // [20000][128]

  char* p = (char*)d_ws;
  auto alloc = [&](size_t bytes) { char* r = p; p += (bytes + 255) & ~(size_t)255; return r; };
  float* Dv   = (float*)alloc((size_t)NN * 4);
  float* De   = (float*)alloc((size_t)NE * 4);
  float* isd  = (float*)alloc((size_t)NN * 4);
  float* es   = (float*)alloc((size_t)NE * 4);
  bf16_t* cat   = (bf16_t*)alloc((size_t)NN * 256 * 2);
  bf16_t* hid1  = (bf16_t*)alloc((size_t)NN * 256 * 2);
  bf16_t* fusedb= (bf16_t*)alloc((size_t)NN * 128 * 2);
  bf16_t* Yt    = (bf16_t*)alloc((size_t)256 * NNP * 2);
  bf16_t* Het   = (bf16_t*)alloc((size_t)256 * NE * 2);
  bf16_t* h     = (bf16_t*)alloc((size_t)NN * 256 * 2);
  bf16_t* pbuf  = (bf16_t*)alloc((size_t)AT_S * 256 * NE * 2);
  bf16_t* Hb    = (bf16_t*)alloc((size_t)NNP * NE * 2);
  bf16_t* psi_wt = (bf16_t*)alloc(65536 * 2);
  bf16_t* phi_wt = (bf16_t*)alloc(32768 * 2);
  bf16_t* g1_wt  = (bf16_t*)alloc(65536 * 2);
  bf16_t* g2_wt  = (bf16_t*)alloc(32768 * 2);
  bf16_t* th1_wt = (bf16_t*)alloc(32768 * 2);
  bf16_t* th2_wt = (bf16_t*)alloc(65536 * 2);

  // zero degree accumulators (Dv..De region)
  hipMemsetAsync(Dv, 0, ((char*)isd - (char*)Dv), stream);

  cvtw_kern<<<1152, 256, 0, stream>>>(psi_w, phi_w, g1_w, g2_w, th1, th2,
                                      psi_wt, phi_wt, g1_wt, g2_wt, th1_wt, th2_wt);
  stats_cvt_kern<<<dim3(64, 160), 256, 0, stream>>>(H, w, Dv, De, Hb);
  finalize_kern<<<79, 256, 0, stream>>>(Dv, De, w, isd, es);

  // front-end MLP chain
  gemm_node_kern<true,  EPI_CAT ><<<dim3(625, 1), 256, 0, stream>>>(x, 512, psi_wt, 512, psi_b, nullptr, cat,       256, nullptr, nullptr);
  gemm_node_kern<true,  EPI_CAT ><<<dim3(625, 1), 256, 0, stream>>>(z, 256, phi_wt, 256, phi_b, nullptr, cat + 128, 256, nullptr, nullptr);
  gemm_node_kern<false, EPI_RELU><<<dim3(625, 2), 256, 0, stream>>>(cat, 256, g1_wt, 256, g1_b, nullptr, hid1, 256, nullptr, nullptr);
  gemm_node_kern<false, EPI_GATE><<<dim3(625, 1), 256, 0, stream>>>(hid1, 256, g2_wt, 256, g2_b, gate_out, fusedb, 128, cat, nullptr);

  // hconv 1
  gemm_node_kern<false, EPI_Y><<<dim3(640, 2), 256, 0, stream>>>(fusedb, 128, th1_wt, 128, nullptr, nullptr, Yt, 0, nullptr, isd);
  at_gemm_kern<<<dim3(32, AT_S), 256, 0, stream>>>(Hb, Yt, pbuf);
  reduce_he<<<4096, 256, 0, stream>>>(pbuf, es, Het);
  out_gemm_kern<<<256, 512, 0, stream>>>(Het, Hb, isd, b1, h);

  // hconv 2
  gemm_node_kern<false, EPI_Y><<<dim3(640, 2), 256, 0, stream>>>(h, 256, th2_wt, 256, nullptr, nullptr, Yt, 0, nullptr, isd);
  at_gemm_kern<<<dim3(32, AT_S), 256, 0, stream>>>(Hb, Yt, pbuf);
  reduce_he<<<4096, 256, 0, stream>>>(pbuf, es, Het);
  out_gemm_kern<<<256, 512, 0, stream>>>(Het, Hb, isd, b2, h);

  logits_kern<<<79, 256, 0, stream>>>(h, out_w, out_b, logits_out);
  (void)in_sizes; (void)n_in; (void)out_size; (void)ws_size;
}

// Round 4
// 1150.714 us; speedup vs baseline: 1.1677x; 1.1154x over previous
//
#include <hip/hip_runtime.h>
#include <hip/hip_bf16.h>

// DF-HGNN fused pipeline v4: fragment-major intermediate layouts so every
// MFMA operand load / result store is a single coalesced wave transaction.
// N=20000, E=4096, IN=512, DET=256, HID=256, HALF=128, OUT=2.

typedef __bf16 bf16_t;
typedef __attribute__((ext_vector_type(8))) __bf16 bf16x8;
typedef __attribute__((ext_vector_type(4))) __bf16 bf16x4;
typedef __attribute__((ext_vector_type(4))) float f32x4;

#define NN 20000
#define NE 4096
#define NNP 20480           // 640*32 padded node extent (zero rows >= NN)
#define NSTEPS 640          // NNP/32
#define AT_S 24             // n-split for H^T @ Y (32 e-blocks x 24 = 768)
// Fragment-major layouts:
//  Yf  [fblk 16][nblk 640][lane 64][8]  : value(f,n) at lane=((n&31)>>3)*16+(f&15), j=n&7
//  Hef [fblk 16][eblk 128][lane 64][8]  : value(f,e) same scheme with k=e
//  part[s][eblk16 256][fblk 16][lane 64][4] : D-frag dump, value(e,f) at
//       lane=(e&15 quad/lq mapping): lane=lq*16+lr holds e=eblk16*16+lq*4+r, f=fblk*16+lr

__device__ __forceinline__ f32x4 mfma16(bf16x8 a, bf16x8 b, f32x4 c) {
  return __builtin_amdgcn_mfma_f32_16x16x32_bf16(a, b, c, 0, 0, 0);
}

// ---------------- fused stats + bf16 cast: Dv, De, Hb[n][e] ----------------
__global__ __launch_bounds__(256) void stats_cvt_kern(const float* __restrict__ H,
                                                      const float* __restrict__ w,
                                                      float* __restrict__ Dv,
                                                      float* __restrict__ De,
                                                      bf16_t* __restrict__ Hb) {
  __shared__ bf16_t tile[128 * 72];
  int t = threadIdx.x;
  long e0 = (long)blockIdx.x * 64;
  long n0 = (long)blockIdx.y * 128;
  int r = t >> 1, ch = t & 1;
  long row = n0 + r;
  float dvp = 0.f;
  bf16_t* dstl = tile + r * 72 + ch * 32;
  bf16x8 loc[4];
  if (row < NN) {
    const float* hp = H + row * NE + e0 + ch * 32;
    const float* wp = w + e0 + ch * 32;
    #pragma unroll
    for (int q = 0; q < 4; ++q) {
      f32x4 u0 = *(const f32x4*)(hp + q * 8);
      f32x4 u1 = *(const f32x4*)(hp + q * 8 + 4);
      f32x4 w0 = *(const f32x4*)(wp + q * 8);
      f32x4 w1 = *(const f32x4*)(wp + q * 8 + 4);
      bf16x8 b;
      #pragma unroll
      for (int j = 0; j < 4; ++j) { b[j] = (__bf16)u0[j]; b[4 + j] = (__bf16)u1[j]; }
      loc[q] = b;
      dvp += u0[0]*w0[0] + u0[1]*w0[1] + u0[2]*w0[2] + u0[3]*w0[3]
           + u1[0]*w1[0] + u1[1]*w1[1] + u1[2]*w1[2] + u1[3]*w1[3];
    }
  } else {
    bf16x8 zz;
    #pragma unroll
    for (int j = 0; j < 8; ++j) zz[j] = (__bf16)0.f;
    #pragma unroll
    for (int q = 0; q < 4; ++q) loc[q] = zz;
  }
  #pragma unroll
  for (int q = 0; q < 4; ++q) *(bf16x8*)(dstl + q * 8) = loc[q];
  {
    bf16_t* hb = Hb + row * NE + e0 + ch * 32;
    #pragma unroll
    for (int q = 0; q < 4; ++q) *(bf16x8*)(hb + q * 8) = loc[q];
  }
  dvp += __shfl_xor(dvp, 1);
  if (ch == 0 && row < NN) atomicAdd(&Dv[row], dvp);
  __syncthreads();
  {
    int c2 = t & 31, rg = t >> 5;
    float s0 = 0.f, s1 = 0.f;
    #pragma unroll
    for (int j = 0; j < 16; ++j) {
      unsigned u = *(const unsigned*)(tile + (rg * 16 + j) * 72 + c2 * 2);
      s0 += __uint_as_float(u << 16);
      s1 += __uint_as_float(u & 0xffff0000u);
    }
    atomicAdd(&De[e0 + c2 * 2], s0);
    atomicAdd(&De[e0 + c2 * 2 + 1], s1);
  }
}

__global__ void finalize_kern(const float* __restrict__ Dv, const float* __restrict__ De,
                              const float* __restrict__ w,
                              float* __restrict__ isd, float* __restrict__ es) {
  int t = blockIdx.x * 256 + threadIdx.x;
  if (t < NN) isd[t] = rsqrtf(fmaxf(Dv[t], 1e-6f));
  if (t < NE) es[t] = w[t] / fmaxf(De[t], 1e-6f);
}

// -------------------------------------------- weight transpose+cast (tiny)
__global__ void cvtw_kern(const float* __restrict__ psi, const float* __restrict__ phi,
                          const float* __restrict__ g1,  const float* __restrict__ g2,
                          const float* __restrict__ th1, const float* __restrict__ th2,
                          bf16_t* dpsi, bf16_t* dphi, bf16_t* dg1, bf16_t* dg2,
                          bf16_t* dth1, bf16_t* dth2) {
  int t = blockIdx.x * 256 + threadIdx.x;
  if (t < 65536) {
    int nc = t >> 9, k = t & 511; dpsi[t] = (__bf16)psi[k * 128 + nc];
  } else if (t < 98304) {
    int i = t - 65536; int nc = i >> 8, k = i & 255; dphi[i] = (__bf16)phi[k * 128 + nc];
  } else if (t < 163840) {
    int i = t - 98304; int nc = i >> 8, k = i & 255; dg1[i] = (__bf16)g1[k * 256 + nc];
  } else if (t < 196608) {
    int i = t - 163840; int nc = i >> 8, k = i & 255; dg2[i] = (__bf16)g2[k * 128 + nc];
  } else if (t < 229376) {
    int i = t - 196608; int nc = i >> 7, k = i & 127; dth1[i] = (__bf16)th1[k * 256 + nc];
  } else if (t < 294912) {
    int i = t - 229376; int nc = i >> 8, k = i & 255; dth2[i] = (__bf16)th2[k * 256 + nc];
  }
}

// --------------------------------------------------- node-feature GEMMs
enum { EPI_CAT = 0, EPI_RELU = 1, EPI_GATE = 2, EPI_Y = 3 };

template<bool AF32, int EPI>
__global__ __launch_bounds__(256) void gemm_node_kern(
    const void* __restrict__ Av, int lda, const bf16_t* __restrict__ Bt, int K,
    const float* __restrict__ bias, float* __restrict__ gate_out,
    bf16_t* __restrict__ dst, int ldc, const bf16_t* __restrict__ cat,
    const float* __restrict__ isd) {
  int tid = threadIdx.x, l = tid & 63, wv = tid >> 6;
  int lr = l & 15, lq = l >> 4;
  int hm = wv >> 1;
  int mo = blockIdx.x * 32 + hm * 16;
  int no = blockIdx.y * 128 + (wv & 1) * 64;
  f32x4 acc[4] = {};
  for (int k0 = 0; k0 < K; k0 += 32) {
    int row = mo + lr;
    bf16x8 a;
    if (row < NN) {
      if constexpr (AF32) {
        const float* ap = (const float*)Av + (long)row * lda + k0 + lq * 8;
        f32x4 u0 = *(const f32x4*)ap, u1 = *(const f32x4*)(ap + 4);
        #pragma unroll
        for (int j = 0; j < 4; ++j) { a[j] = (__bf16)u0[j]; a[j + 4] = (__bf16)u1[j]; }
      } else {
        a = *(const bf16x8*)((const bf16_t*)Av + (long)row * lda + k0 + lq * 8);
      }
    } else {
      #pragma unroll
      for (int j = 0; j < 8; ++j) a[j] = (__bf16)0.f;
    }
    #pragma unroll
    for (int ni = 0; ni < 4; ++ni) {
      bf16x8 b = *(const bf16x8*)(Bt + (long)(no + ni * 16 + lr) * K + k0 + lq * 8);
      acc[ni] = mfma16(a, b, acc[ni]);
    }
  }
  #pragma unroll
  for (int ni = 0; ni < 4; ++ni) {
    int colf = no + ni * 16 + lr;
    int rb = mo + lq * 4;
    f32x4 v = acc[ni];
    if constexpr (EPI == EPI_CAT) {
      float bs = bias[colf];
      for (int r = 0; r < 4; ++r) { int n = rb + r;
        if (n < NN) dst[(long)n * ldc + colf] = (__bf16)(v[r] + bs); }
    } else if constexpr (EPI == EPI_RELU) {
      float bs = bias[colf];
      for (int r = 0; r < 4; ++r) { int n = rb + r;
        if (n < NN) { float xx = v[r] + bs; dst[(long)n * ldc + colf] = (__bf16)(xx > 0.f ? xx : 0.f); } }
    } else if constexpr (EPI == EPI_GATE) {
      float bs = bias[colf];
      for (int r = 0; r < 4; ++r) {
        int n = rb + r;
        if (n < NN) {
          float g = 1.f / (1.f + __expf(-(v[r] + bs)));
          gate_out[(long)n * 128 + colf] = g;
          float px = (float)cat[(long)n * 256 + colf];
          float pz = (float)cat[(long)n * 256 + 128 + colf];
          dst[(long)n * 128 + colf] = (__bf16)(g * pz + (1.f - g) * px);
        }
      }
    } else {  // EPI_Y: fragment-major Yf, one coalesced 8B store per ni
      int fblk = (no >> 4) + ni;
      int nblk = blockIdx.x;
      int lanep = (hm * 2 + (lq >> 1)) * 16 + lr;
      bf16x4 pk;
      for (int r = 0; r < 4; ++r) {
        int nr = rb + r;
        float sc = (nr < NN) ? isd[nr] : 0.f;
        pk[r] = (__bf16)(v[r] * sc);
      }
      *(bf16x4*)(dst + (((long)fblk * 640 + nblk) * 64 + lanep) * 8 + (lq & 1) * 4) = pk;
    }
  }
}

// --------------------------------------------- He partials: fragment-major
// He[e][f] = sum_n Hb[n][e]*Y[f][n]. Hb staged+transposed through LDS with
// coalesced 256B-segment loads and a register prefetch of the next stripe.
__global__ __launch_bounds__(256) void at_gemm_kern(const bf16_t* __restrict__ Hb,
                                                    const bf16_t* __restrict__ Yf,
                                                    bf16_t* __restrict__ part) {
  __shared__ bf16_t T[128 * 40];       // [e_local][32 n + pad], 80B rows
  int t = threadIdx.x, l = t & 63, wv = t >> 6;
  int lr = l & 15, lq = l >> 4;
  int e0 = blockIdx.x * 128;
  int s0 = (blockIdx.y * NSTEPS) / AT_S;
  int s1 = ((blockIdx.y + 1) * NSTEPS) / AT_S;
  int rp = t >> 4;                     // row-pair 0..15
  int ck = t & 15;                     // 8-e column chunk
  f32x4 acc[2][16] = {};
  const bf16_t* src = Hb + ((long)s0 * 32 + 2 * rp) * NE + e0 + ck * 8;
  bf16x8 ra = *(const bf16x8*)src;
  bf16x8 rb = *(const bf16x8*)(src + NE);
  for (int s = s0; s < s1; ++s) {
    __syncthreads();
    #pragma unroll
    for (int j = 0; j < 8; ++j) {
      int jj = (j + ck) & 7;           // rotation -> exact 2-way banks (free)
      int el = ck * 8 + jj;
      unsigned lo = (unsigned)__builtin_bit_cast(unsigned short, (__bf16)ra[jj]);
      unsigned hi = (unsigned)__builtin_bit_cast(unsigned short, (__bf16)rb[jj]);
      *(unsigned*)(T + el * 40 + rp * 2) = lo | (hi << 16);
    }
    __syncthreads();
    if (s + 1 < s1) {                  // prefetch next stripe under MFMA
      src += 32 * (long)NE;
      ra = *(const bf16x8*)src;
      rb = *(const bf16x8*)(src + NE);
    }
    bf16x8 a0 = *(const bf16x8*)(T + (wv * 32 + lr) * 40 + lq * 8);
    bf16x8 a1 = *(const bf16x8*)(T + (wv * 32 + 16 + lr) * 40 + lq * 8);
    const bf16_t* bp = Yf + ((long)s * 64 + l) * 8;
    #pragma unroll
    for (int ni = 0; ni < 16; ++ni) {
      bf16x8 b = *(const bf16x8*)(bp + (long)ni * 640 * 512);
      acc[0][ni] = mfma16(a0, b, acc[0][ni]);
      acc[1][ni] = mfma16(a1, b, acc[1][ni]);
    }
  }
  bf16_t* pp = part + (long)blockIdx.y * (256 * 4096);
  #pragma unroll
  for (int mi = 0; mi < 2; ++mi) {
    int eblk16 = (e0 >> 4) + wv * 2 + mi;
    #pragma unroll
    for (int ni = 0; ni < 16; ++ni) {
      f32x4 v = acc[mi][ni];
      bf16x4 pk;
      for (int r = 0; r < 4; ++r) pk[r] = (__bf16)v[r];
      *(bf16x4*)(pp + (((long)eblk16 * 16 + ni) * 64 + l) * 4) = pk;
    }
  }
}

// Hef[f][e] (fragment-major) = es[e] * sum_s part[s][...]
__global__ __launch_bounds__(256) void reduce_he(const bf16_t* __restrict__ part,
                                                 const float* __restrict__ es,
                                                 bf16_t* __restrict__ Hef) {
  int u = blockIdx.x * 256 + threadIdx.x;      // 0..262143
  int lane = u & 63, tile = u >> 6;
  int fblk = tile & 15, eblk16 = tile >> 4;
  int lr = lane & 15, lq = lane >> 4;
  int e_base = eblk16 * 16 + lq * 4;
  float a0 = 0.f, a1 = 0.f, a2 = 0.f, a3 = 0.f;
  #pragma unroll
  for (int s = 0; s < AT_S; ++s) {
    bf16x4 v = *(const bf16x4*)(part + (long)s * (256 * 4096) + (long)u * 4);
    a0 += (float)v[0]; a1 += (float)v[1]; a2 += (float)v[2]; a3 += (float)v[3];
  }
  f32x4 e4 = *(const f32x4*)(es + e_base);
  bf16x4 pk;
  pk[0] = (__bf16)(a0 * e4[0]); pk[1] = (__bf16)(a1 * e4[1]);
  pk[2] = (__bf16)(a2 * e4[2]); pk[3] = (__bf16)(a3 * e4[3]);
  int eblk32 = eblk16 >> 1;
  int lanep = ((eblk16 & 1) * 2 + (lq >> 1)) * 16 + lr;
  long slot = (((long)fblk * 128 + eblk32) * 64 + lanep) * 8 + (lq & 1) * 4;
  *(bf16x4*)(Hef + slot) = pk;
}

// -------- h[n][f] = relu(isd[n]*(Hb[n]@He) + bias) ------------------------
// 256 blocks (1/CU), 8 waves, wave tile 80n x 32f; A streamed from HBM,
// B = Hef fragments (single coalesced 1KB load each), reg double-buffer.
__global__ __launch_bounds__(512) void out_gemm_kern(const bf16_t* __restrict__ Hef,
                                                     const bf16_t* __restrict__ Hb,
                                                     const float* __restrict__ isd,
                                                     const float* __restrict__ bias,
                                                     bf16_t* __restrict__ h) {
  int t = threadIdx.x, l = t & 63, wv = t >> 6;
  int lr = l & 15, lq = l >> 4;
  long r0 = (long)blockIdx.x * 80;
  int fo = wv * 32;
  f32x4 acc[5][2] = {};
  const bf16_t* ap = Hb + (r0 + lr) * (long)NE + lq * 8;
  const bf16_t* bp = Hef + (long)(wv * 2) * 65536 + l * 8;
  bf16x8 a[5], b[2];
  #pragma unroll
  for (int mi = 0; mi < 5; ++mi) a[mi] = *(const bf16x8*)(ap + (long)mi * 16 * NE);
  b[0] = *(const bf16x8*)(bp);
  b[1] = *(const bf16x8*)(bp + 65536);
  for (int k0 = 32; k0 < NE; k0 += 32) {
    int eblk = k0 >> 5;
    bf16x8 an[5], bn[2];
    #pragma unroll
    for (int mi = 0; mi < 5; ++mi) an[mi] = *(const bf16x8*)(ap + (long)mi * 16 * NE + k0);
    bn[0] = *(const bf16x8*)(bp + eblk * 512);
    bn[1] = *(const bf16x8*)(bp + 65536 + eblk * 512);
    #pragma unroll
    for (int mi = 0; mi < 5; ++mi) {
      acc[mi][0] = mfma16(a[mi], b[0], acc[mi][0]);
      acc[mi][1] = mfma16(a[mi], b[1], acc[mi][1]);
    }
    #pragma unroll
    for (int mi = 0; mi < 5; ++mi) a[mi] = an[mi];
    b[0] = bn[0]; b[1] = bn[1];
  }
  #pragma unroll
  for (int mi = 0; mi < 5; ++mi) {
    acc[mi][0] = mfma16(a[mi], b[0], acc[mi][0]);
    acc[mi][1] = mfma16(a[mi], b[1], acc[mi][1]);
  }
  #pragma unroll
  for (int mi = 0; mi < 5; ++mi) {
    long nb = r0 + mi * 16 + lq * 4;
    #pragma unroll
    for (int ni = 0; ni < 2; ++ni) {
      int f = fo + ni * 16 + lr;
      float bs = bias[f];
      #pragma unroll
      for (int r = 0; r < 4; ++r) {
        long n = nb + r;
        if (n < NN) {
          float vv = acc[mi][ni][r] * isd[n] + bs;
          h[n * 256 + f] = (__bf16)(vv > 0.f ? vv : 0.f);
        }
      }
    }
  }
}

// ------------------------------------------- logits[n][2] = h[n]@out_w + b
__global__ __launch_bounds__(256) void logits_kern(const bf16_t* __restrict__ h,
                                                   const float* __restrict__ ow,
                                                   const float* __restrict__ ob,
                                                   float* __restrict__ out) {
  __shared__ float lw[512];
  int t = threadIdx.x;
  lw[t * 2] = ow[t * 2];
  lw[t * 2 + 1] = ow[t * 2 + 1];
  __syncthreads();
  int n = blockIdx.x * 256 + t;
  if (n >= NN) return;
  float a0 = ob[0], a1 = ob[1];
  const bf16x8* hp = (const bf16x8*)(h + (long)n * 256);
  for (int c = 0; c < 32; ++c) {
    bf16x8 v = hp[c];
    #pragma unroll
    for (int j = 0; j < 8; ++j) {
      float f = (float)v[j];
      a0 += f * lw[(c * 8 + j) * 2];
      a1 += f * lw[(c * 8 + j) * 2 + 1];
    }
  }
  out[n * 2] = a0;
  out[n * 2 + 1] = a1;
}

// ============================================================== launcher
extern "C" void kernel_launch(void* const* d_in, const int* in_sizes, int n_in,
                              void* d_out, int out_size, void* d_ws, size_t ws_size,
                              hipStream_t stream) {
  const float* x    = (const float*)d_in[0];
  const float* z    = (const float*)d_in[1];
  const float* H    = (const float*)d_in[2];
  const float* w    = (const float*)d_in[3];
  const float* psi_w = (const float*)d_in[4];
  const float* psi_b = (const float*)d_in[5];
  const float* phi_w = (const float*)d_in[6];
  const float* phi_b = (const float*)d_in[7];
  const float* g1_w  = (const float*)d_in[8];
  const float* g1_b  = (const float*)d_in[9];
  const float* g2_w  = (const float*)d_in[10];
  const float* g2_b  = (const float*)d_in[11];
  const float* th1   = (const float*)d_in[12];
  const float* b1    = (const float*)d_in[13];
  const float* th2   = (const float*)d_in[14];
  const float* b2    = (const float*)d_in[15];
  const float* out_w = (const float*)d_in[16];
  const float* out_b = (const float*)d_in[17];

  float* logits_out = (float*)d_out;                 // [20000][2]
  float* gate_out   = logits_out + (size_t)NN * 2;   // [20000][128]

  char* p = (char*)d_ws;
  auto alloc = [&](size_t bytes) { char* r = p; p += (bytes + 255) & ~(size_t)255; return r; };
  float* Dv   = (float*)alloc((size_t)NN * 4);
  float* De   = (float*)alloc((size_t)NE * 4);
  float* isd  = (float*)alloc((size_t)NN * 4);
  float* es   = (float*)alloc((size_t)NE * 4);
  bf16_t* cat   = (bf16_t*)alloc((size_t)NN * 256 * 2);
  bf16_t* hid1  = (bf16_t*)alloc((size_t)NN * 256 * 2);
  bf16_t* fusedb= (bf16_t*)alloc((size_t)NN * 128 * 2);
  bf16_t* Yf    = (bf16_t*)alloc((size_t)16 * 640 * 512 * 2);   // 10.49 MB
  bf16_t* Hef   = (bf16_t*)alloc((size_t)16 * 128 * 512 * 2);   // 2.1 MB
  bf16_t* h     = (bf16_t*)alloc((size_t)NN * 256 * 2);
  bf16_t* pbuf  = (bf16_t*)alloc((size_t)AT_S * 256 * 4096 * 2);
  bf16_t* Hb    = (bf16_t*)alloc((size_t)NNP * NE * 2);
  bf16_t* psi_wt = (bf16_t*)alloc(65536 * 2);
  bf16_t* phi_wt = (bf16_t*)alloc(32768 * 2);
  bf16_t* g1_wt  = (bf16_t*)alloc(65536 * 2);
  bf16_t* g2_wt  = (bf16_t*)alloc(32768 * 2);
  bf16_t* th1_wt = (bf16_t*)alloc(32768 * 2);
  bf16_t* th2_wt = (bf16_t*)alloc(65536 * 2);

  hipMemsetAsync(Dv, 0, ((char*)isd - (char*)Dv), stream);

  cvtw_kern<<<1152, 256, 0, stream>>>(psi_w, phi_w, g1_w, g2_w, th1, th2,
                                      psi_wt, phi_wt, g1_wt, g2_wt, th1_wt, th2_wt);
  stats_cvt_kern<<<dim3(64, 160), 256, 0, stream>>>(H, w, Dv, De, Hb);
  finalize_kern<<<79, 256, 0, stream>>>(Dv, De, w, isd, es);

  // front-end MLP chain
  gemm_node_kern<true,  EPI_CAT ><<<dim3(625, 1), 256, 0, stream>>>(x, 512, psi_wt, 512, psi_b, nullptr, cat,       256, nullptr, nullptr);
  gemm_node_kern<true,  EPI_CAT ><<<dim3(625, 1), 256, 0, stream>>>(z, 256, phi_wt, 256, phi_b, nullptr, cat + 128, 256, nullptr, nullptr);
  gemm_node_kern<false, EPI_RELU><<<dim3(625, 2), 256, 0, stream>>>(cat, 256, g1_wt, 256, g1_b, nullptr, hid1, 256, nullptr, nullptr);
  gemm_node_kern<false, EPI_GATE><<<dim3(625, 1), 256, 0, stream>>>(hid1, 256, g2_wt, 256, g2_b, gate_out, fusedb, 128, cat, nullptr);

  // hconv 1
  gemm_node_kern<false, EPI_Y><<<dim3(640, 2), 256, 0, stream>>>(fusedb, 128, th1_wt, 128, nullptr, nullptr, Yf, 0, nullptr, isd);
  at_gemm_kern<<<dim3(32, AT_S), 256, 0, stream>>>(Hb, Yf, pbuf);
  reduce_he<<<1024, 256, 0, stream>>>(pbuf, es, Hef);
  out_gemm_kern<<<256, 512, 0, stream>>>(Hef, Hb, isd, b1, h);

  // hconv 2
  gemm_node_kern<false, EPI_Y><<<dim3(640, 2), 256, 0, stream>>>(h, 256, th2_wt, 256, nullptr, nullptr, Yf, 0, nullptr, isd);
  at_gemm_kern<<<dim3(32, AT_S), 256, 0, stream>>>(Hb, Yf, pbuf);
  reduce_he<<<1024, 256, 0, stream>>>(pbuf, es, Hef);
  out_gemm_kern<<<256, 512, 0, stream>>>(Hef, Hb, isd, b2, h);

  logits_kern<<<79, 256, 0, stream>>>(h, out_w, out_b, logits_out);
  (void)in_sizes; (void)n_in; (void)out_size; (void)ws_size;
}

// Round 5
// 813.617 us; speedup vs baseline: 1.6515x; 1.4143x over previous
//
#include <hip/hip_runtime.h>
#include <hip/hip_bf16.h>

// DF-HGNN fused pipeline v5: at_gemm restructured to 8-wave 128e x 256f tile,
// f split across waves (4 B-frags/wave from L2), BK=64 LDS transpose staging.
// N=20000, E=4096, IN=512, DET=256, HID=256, HALF=128, OUT=2.

typedef __bf16 bf16_t;
typedef __attribute__((ext_vector_type(8))) __bf16 bf16x8;
typedef __attribute__((ext_vector_type(4))) __bf16 bf16x4;
typedef __attribute__((ext_vector_type(4))) float f32x4;

#define NN 20000
#define NE 4096
#define NNP 20480           // 640*32 padded node extent (zero rows >= NN)
#define AT_S 16             // n-split for H^T @ Y (32 e-blocks x 16 = 512 = 2/CU)
// Fragment-major layouts:
//  Yf  [fblk 16][nblk 640][lane 64][8]  : value(f,n) at lane=((n&31)>>3)*16+(f&15), j=n&7
//  Hef [fblk 16][eblk 128][lane 64][8]  : value(f,e) same scheme with k=e
//  part[s][tile=eblk16*16+fblk][lane 64][4] : D-frag dump; e=eblk16*16+lq*4+r, f=fblk*16+lr

__device__ __forceinline__ f32x4 mfma16(bf16x8 a, bf16x8 b, f32x4 c) {
  return __builtin_amdgcn_mfma_f32_16x16x32_bf16(a, b, c, 0, 0, 0);
}

// ---------------- fused stats + bf16 cast: Dv, De, Hb[n][e] ----------------
__global__ __launch_bounds__(256) void stats_cvt_kern(const float* __restrict__ H,
                                                      const float* __restrict__ w,
                                                      float* __restrict__ Dv,
                                                      float* __restrict__ De,
                                                      bf16_t* __restrict__ Hb) {
  __shared__ bf16_t tile[128 * 72];
  int t = threadIdx.x;
  long e0 = (long)blockIdx.x * 64;
  long n0 = (long)blockIdx.y * 128;
  int r = t >> 1, ch = t & 1;
  long row = n0 + r;
  float dvp = 0.f;
  bf16_t* dstl = tile + r * 72 + ch * 32;
  bf16x8 loc[4];
  if (row < NN) {
    const float* hp = H + row * NE + e0 + ch * 32;
    const float* wp = w + e0 + ch * 32;
    #pragma unroll
    for (int q = 0; q < 4; ++q) {
      f32x4 u0 = *(const f32x4*)(hp + q * 8);
      f32x4 u1 = *(const f32x4*)(hp + q * 8 + 4);
      f32x4 w0 = *(const f32x4*)(wp + q * 8);
      f32x4 w1 = *(const f32x4*)(wp + q * 8 + 4);
      bf16x8 b;
      #pragma unroll
      for (int j = 0; j < 4; ++j) { b[j] = (__bf16)u0[j]; b[4 + j] = (__bf16)u1[j]; }
      loc[q] = b;
      dvp += u0[0]*w0[0] + u0[1]*w0[1] + u0[2]*w0[2] + u0[3]*w0[3]
           + u1[0]*w1[0] + u1[1]*w1[1] + u1[2]*w1[2] + u1[3]*w1[3];
    }
  } else {
    bf16x8 zz;
    #pragma unroll
    for (int j = 0; j < 8; ++j) zz[j] = (__bf16)0.f;
    #pragma unroll
    for (int q = 0; q < 4; ++q) loc[q] = zz;
  }
  #pragma unroll
  for (int q = 0; q < 4; ++q) *(bf16x8*)(dstl + q * 8) = loc[q];
  {
    bf16_t* hb = Hb + row * NE + e0 + ch * 32;
    #pragma unroll
    for (int q = 0; q < 4; ++q) *(bf16x8*)(hb + q * 8) = loc[q];
  }
  dvp += __shfl_xor(dvp, 1);
  if (ch == 0 && row < NN) atomicAdd(&Dv[row], dvp);
  __syncthreads();
  {
    int c2 = t & 31, rg = t >> 5;
    float s0 = 0.f, s1 = 0.f;
    #pragma unroll
    for (int j = 0; j < 16; ++j) {
      unsigned u = *(const unsigned*)(tile + (rg * 16 + j) * 72 + c2 * 2);
      s0 += __uint_as_float(u << 16);
      s1 += __uint_as_float(u & 0xffff0000u);
    }
    atomicAdd(&De[e0 + c2 * 2], s0);
    atomicAdd(&De[e0 + c2 * 2 + 1], s1);
  }
}

__global__ void finalize_kern(const float* __restrict__ Dv, const float* __restrict__ De,
                              const float* __restrict__ w,
                              float* __restrict__ isd, float* __restrict__ es) {
  int t = blockIdx.x * 256 + threadIdx.x;
  if (t < NN) isd[t] = rsqrtf(fmaxf(Dv[t], 1e-6f));
  if (t < NE) es[t] = w[t] / fmaxf(De[t], 1e-6f);
}

// -------------------------------------------- weight transpose+cast (tiny)
__global__ void cvtw_kern(const float* __restrict__ psi, const float* __restrict__ phi,
                          const float* __restrict__ g1,  const float* __restrict__ g2,
                          const float* __restrict__ th1, const float* __restrict__ th2,
                          bf16_t* dpsi, bf16_t* dphi, bf16_t* dg1, bf16_t* dg2,
                          bf16_t* dth1, bf16_t* dth2) {
  int t = blockIdx.x * 256 + threadIdx.x;
  if (t < 65536) {
    int nc = t >> 9, k = t & 511; dpsi[t] = (__bf16)psi[k * 128 + nc];
  } else if (t < 98304) {
    int i = t - 65536; int nc = i >> 8, k = i & 255; dphi[i] = (__bf16)phi[k * 128 + nc];
  } else if (t < 163840) {
    int i = t - 98304; int nc = i >> 8, k = i & 255; dg1[i] = (__bf16)g1[k * 256 + nc];
  } else if (t < 196608) {
    int i = t - 163840; int nc = i >> 8, k = i & 255; dg2[i] = (__bf16)g2[k * 128 + nc];
  } else if (t < 229376) {
    int i = t - 196608; int nc = i >> 7, k = i & 127; dth1[i] = (__bf16)th1[k * 256 + nc];
  } else if (t < 294912) {
    int i = t - 229376; int nc = i >> 8, k = i & 255; dth2[i] = (__bf16)th2[k * 256 + nc];
  }
}

// --------------------------------------------------- node-feature GEMMs
enum { EPI_CAT = 0, EPI_RELU = 1, EPI_GATE = 2, EPI_Y = 3 };

template<bool AF32, int EPI>
__global__ __launch_bounds__(256) void gemm_node_kern(
    const void* __restrict__ Av, int lda, const bf16_t* __restrict__ Bt, int K,
    const float* __restrict__ bias, float* __restrict__ gate_out,
    bf16_t* __restrict__ dst, int ldc, const bf16_t* __restrict__ cat,
    const float* __restrict__ isd) {
  int tid = threadIdx.x, l = tid & 63, wv = tid >> 6;
  int lr = l & 15, lq = l >> 4;
  int hm = wv >> 1;
  int mo = blockIdx.x * 32 + hm * 16;
  int no = blockIdx.y * 128 + (wv & 1) * 64;
  f32x4 acc[4] = {};
  for (int k0 = 0; k0 < K; k0 += 32) {
    int row = mo + lr;
    bf16x8 a;
    if (row < NN) {
      if constexpr (AF32) {
        const float* ap = (const float*)Av + (long)row * lda + k0 + lq * 8;
        f32x4 u0 = *(const f32x4*)ap, u1 = *(const f32x4*)(ap + 4);
        #pragma unroll
        for (int j = 0; j < 4; ++j) { a[j] = (__bf16)u0[j]; a[j + 4] = (__bf16)u1[j]; }
      } else {
        a = *(const bf16x8*)((const bf16_t*)Av + (long)row * lda + k0 + lq * 8);
      }
    } else {
      #pragma unroll
      for (int j = 0; j < 8; ++j) a[j] = (__bf16)0.f;
    }
    #pragma unroll
    for (int ni = 0; ni < 4; ++ni) {
      bf16x8 b = *(const bf16x8*)(Bt + (long)(no + ni * 16 + lr) * K + k0 + lq * 8);
      acc[ni] = mfma16(a, b, acc[ni]);
    }
  }
  #pragma unroll
  for (int ni = 0; ni < 4; ++ni) {
    int colf = no + ni * 16 + lr;
    int rb = mo + lq * 4;
    f32x4 v = acc[ni];
    if constexpr (EPI == EPI_CAT) {
      float bs = bias[colf];
      for (int r = 0; r < 4; ++r) { int n = rb + r;
        if (n < NN) dst[(long)n * ldc + colf] = (__bf16)(v[r] + bs); }
    } else if constexpr (EPI == EPI_RELU) {
      float bs = bias[colf];
      for (int r = 0; r < 4; ++r) { int n = rb + r;
        if (n < NN) { float xx = v[r] + bs; dst[(long)n * ldc + colf] = (__bf16)(xx > 0.f ? xx : 0.f); } }
    } else if constexpr (EPI == EPI_GATE) {
      float bs = bias[colf];
      for (int r = 0; r < 4; ++r) {
        int n = rb + r;
        if (n < NN) {
          float g = 1.f / (1.f + __expf(-(v[r] + bs)));
          gate_out[(long)n * 128 + colf] = g;
          float px = (float)cat[(long)n * 256 + colf];
          float pz = (float)cat[(long)n * 256 + 128 + colf];
          dst[(long)n * 128 + colf] = (__bf16)(g * pz + (1.f - g) * px);
        }
      }
    } else {  // EPI_Y: fragment-major Yf, coalesced 8B store per ni
      int fblk = (no >> 4) + ni;
      int nblk = blockIdx.x;
      int lanep = (hm * 2 + (lq >> 1)) * 16 + lr;
      bf16x4 pk;
      for (int r = 0; r < 4; ++r) {
        int nr = rb + r;
        float sc = (nr < NN) ? isd[nr] : 0.f;
        pk[r] = (__bf16)(v[r] * sc);
      }
      *(bf16x4*)(dst + (((long)fblk * 640 + nblk) * 64 + lanep) * 8 + (lq & 1) * 4) = pk;
    }
  }
}

// --------------------------------------------- He partials: fragment-major
// He[e][f] = sum_n Hb[n][e]*Y[f][n]. 8 waves, block tile 128e x 256f,
// wave tile 64e x 64f (acc[4][4]=64 VGPR). BK=64 per barrier pair.
// A: Hb transposed through LDS (rotation-packed u32 writes, 2-way/free).
// B: 4 Yf fragments per wave, direct from L2 (slice shared by all e-blocks).
__global__ __launch_bounds__(512) void at_gemm_kern(const bf16_t* __restrict__ Hb,
                                                    const bf16_t* __restrict__ Yf,
                                                    bf16_t* __restrict__ part) {
  __shared__ bf16_t T[128 * 72];       // [e_local][64 n + pad]
  int t = threadIdx.x, l = t & 63, wv = t >> 6;
  int lr = l & 15, lq = l >> 4;
  int eh = wv >> 2, fq = wv & 3;       // wave: e-half, f-quarter
  int e0 = blockIdx.x * 128;
  int s0 = blockIdx.y * 20, s1 = s0 + 20;   // BK64 steps (320 total / 16 splits)
  int rp = t >> 4;                     // row-pair 0..31 (64 rows)
  int ck = t & 15;                     // 8-e column chunk
  f32x4 acc[4][4] = {};
  const bf16_t* src = Hb + ((long)s0 * 64 + 2 * rp) * NE + e0 + ck * 8;
  bf16x8 ra = *(const bf16x8*)src;
  bf16x8 rb = *(const bf16x8*)(src + NE);
  for (int s = s0; s < s1; ++s) {
    __syncthreads();
    #pragma unroll
    for (int j = 0; j < 8; ++j) {
      int jj = (j + ck) & 7;           // rotation -> 32 banks, exact 2-way (free)
      int el = ck * 8 + jj;
      unsigned lo = (unsigned)__builtin_bit_cast(unsigned short, (__bf16)ra[jj]);
      unsigned hi = (unsigned)__builtin_bit_cast(unsigned short, (__bf16)rb[jj]);
      *(unsigned*)(T + el * 72 + rp * 2) = lo | (hi << 16);
    }
    __syncthreads();
    if (s + 1 < s1) {                  // prefetch next stripe under MFMA
      src += 64 * (long)NE;
      ra = *(const bf16x8*)src;
      rb = *(const bf16x8*)(src + NE);
    }
    #pragma unroll
    for (int k32 = 0; k32 < 2; ++k32) {
      bf16x8 a[4], b[4];
      #pragma unroll
      for (int ni = 0; ni < 4; ++ni)
        a[ni] = *(const bf16x8*)(T + (eh * 64 + ni * 16 + lr) * 72 + k32 * 32 + lq * 8);
      const bf16_t* bp = Yf + ((long)(s * 2 + k32) * 64 + l) * 8;
      #pragma unroll
      for (int ni = 0; ni < 4; ++ni)
        b[ni] = *(const bf16x8*)(bp + (long)(fq * 4 + ni) * 640 * 512);
      #pragma unroll
      for (int ae = 0; ae < 4; ++ae)
        #pragma unroll
        for (int bf = 0; bf < 4; ++bf)
          acc[ae][bf] = mfma16(a[ae], b[bf], acc[ae][bf]);
    }
  }
  bf16_t* pp = part + (long)blockIdx.y * (256 * 4096);
  #pragma unroll
  for (int ae = 0; ae < 4; ++ae) {
    int eblk16 = (e0 >> 4) + eh * 4 + ae;
    #pragma unroll
    for (int bf = 0; bf < 4; ++bf) {
      int fblk = fq * 4 + bf;
      f32x4 v = acc[ae][bf];
      bf16x4 pk;
      for (int r = 0; r < 4; ++r) pk[r] = (__bf16)v[r];
      *(bf16x4*)(pp + (((long)eblk16 * 16 + fblk) * 64 + l) * 4) = pk;
    }
  }
}

// Hef[f][e] (fragment-major) = es[e] * sum_s part[s][...]
__global__ __launch_bounds__(256) void reduce_he(const bf16_t* __restrict__ part,
                                                 const float* __restrict__ es,
                                                 bf16_t* __restrict__ Hef) {
  int u = blockIdx.x * 256 + threadIdx.x;      // 0..262143
  int lane = u & 63, tile = u >> 6;
  int fblk = tile & 15, eblk16 = tile >> 4;
  int lr = lane & 15, lq = lane >> 4;
  int e_base = eblk16 * 16 + lq * 4;
  float a0 = 0.f, a1 = 0.f, a2 = 0.f, a3 = 0.f;
  #pragma unroll
  for (int s = 0; s < AT_S; ++s) {
    bf16x4 v = *(const bf16x4*)(part + (long)s * (256 * 4096) + (long)u * 4);
    a0 += (float)v[0]; a1 += (float)v[1]; a2 += (float)v[2]; a3 += (float)v[3];
  }
  f32x4 e4 = *(const f32x4*)(es + e_base);
  bf16x4 pk;
  pk[0] = (__bf16)(a0 * e4[0]); pk[1] = (__bf16)(a1 * e4[1]);
  pk[2] = (__bf16)(a2 * e4[2]); pk[3] = (__bf16)(a3 * e4[3]);
  int eblk32 = eblk16 >> 1;
  int lanep = ((eblk16 & 1) * 2 + (lq >> 1)) * 16 + lr;
  long slot = (((long)fblk * 128 + eblk32) * 64 + lanep) * 8 + (lq & 1) * 4;
  *(bf16x4*)(Hef + slot) = pk;
}

// -------- h[n][f] = relu(isd[n]*(Hb[n]@He) + bias) ------------------------
__global__ __launch_bounds__(512) void out_gemm_kern(const bf16_t* __restrict__ Hef,
                                                     const bf16_t* __restrict__ Hb,
                                                     const float* __restrict__ isd,
                                                     const float* __restrict__ bias,
                                                     bf16_t* __restrict__ h) {
  int t = threadIdx.x, l = t & 63, wv = t >> 6;
  int lr = l & 15, lq = l >> 4;
  long r0 = (long)blockIdx.x * 80;
  int fo = wv * 32;
  f32x4 acc[5][2] = {};
  const bf16_t* ap = Hb + (r0 + lr) * (long)NE + lq * 8;
  const bf16_t* bp = Hef + (long)(wv * 2) * 65536 + l * 8;
  bf16x8 a[5], b[2];
  #pragma unroll
  for (int mi = 0; mi < 5; ++mi) a[mi] = *(const bf16x8*)(ap + (long)mi * 16 * NE);
  b[0] = *(const bf16x8*)(bp);
  b[1] = *(const bf16x8*)(bp + 65536);
  for (int k0 = 32; k0 < NE; k0 += 32) {
    int eblk = k0 >> 5;
    bf16x8 an[5], bn[2];
    #pragma unroll
    for (int mi = 0; mi < 5; ++mi) an[mi] = *(const bf16x8*)(ap + (long)mi * 16 * NE + k0);
    bn[0] = *(const bf16x8*)(bp + eblk * 512);
    bn[1] = *(const bf16x8*)(bp + 65536 + eblk * 512);
    #pragma unroll
    for (int mi = 0; mi < 5; ++mi) {
      acc[mi][0] = mfma16(a[mi], b[0], acc[mi][0]);
      acc[mi][1] = mfma16(a[mi], b[1], acc[mi][1]);
    }
    #pragma unroll
    for (int mi = 0; mi < 5; ++mi) a[mi] = an[mi];
    b[0] = bn[0]; b[1] = bn[1];
  }
  #pragma unroll
  for (int mi = 0; mi < 5; ++mi) {
    acc[mi][0] = mfma16(a[mi], b[0], acc[mi][0]);
    acc[mi][1] = mfma16(a[mi], b[1], acc[mi][1]);
  }
  #pragma unroll
  for (int mi = 0; mi < 5; ++mi) {
    long nb = r0 + mi * 16 + lq * 4;
    #pragma unroll
    for (int ni = 0; ni < 2; ++ni) {
      int f = fo + ni * 16 + lr;
      float bs = bias[f];
      #pragma unroll
      for (int r = 0; r < 4; ++r) {
        long n = nb + r;
        if (n < NN) {
          float vv = acc[mi][ni][r] * isd[n] + bs;
          h[n * 256 + f] = (__bf16)(vv > 0.f ? vv : 0.f);
        }
      }
    }
  }
}

// ------------------------------------------- logits[n][2] = h[n]@out_w + b
__global__ __launch_bounds__(256) void logits_kern(const bf16_t* __restrict__ h,
                                                   const float* __restrict__ ow,
                                                   const float* __restrict__ ob,
                                                   float* __restrict__ out) {
  __shared__ float lw[512];
  int t = threadIdx.x;
  lw[t * 2] = ow[t * 2];
  lw[t * 2 + 1] = ow[t * 2 + 1];
  __syncthreads();
  int n = blockIdx.x * 256 + t;
  if (n >= NN) return;
  float a0 = ob[0], a1 = ob[1];
  const bf16x8* hp = (const bf16x8*)(h + (long)n * 256);
  for (int c = 0; c < 32; ++c) {
    bf16x8 v = hp[c];
    #pragma unroll
    for (int j = 0; j < 8; ++j) {
      float f = (float)v[j];
      a0 += f * lw[(c * 8 + j) * 2];
      a1 += f * lw[(c * 8 + j) * 2 + 1];
    }
  }
  out[n * 2] = a0;
  out[n * 2 + 1] = a1;
}

// ============================================================== launcher
extern "C" void kernel_launch(void* const* d_in, const int* in_sizes, int n_in,
                              void* d_out, int out_size, void* d_ws, size_t ws_size,
                              hipStream_t stream) {
  const float* x    = (const float*)d_in[0];
  const float* z    = (const float*)d_in[1];
  const float* H    = (const float*)d_in[2];
  const float* w    = (const float*)d_in[3];
  const float* psi_w = (const float*)d_in[4];
  const float* psi_b = (const float*)d_in[5];
  const float* phi_w = (const float*)d_in[6];
  const float* phi_b = (const float*)d_in[7];
  const float* g1_w  = (const float*)d_in[8];
  const float* g1_b  = (const float*)d_in[9];
  const float* g2_w  = (const float*)d_in[10];
  const float* g2_b  = (const float*)d_in[11];
  const float* th1   = (const float*)d_in[12];
  const float* b1    = (const float*)d_in[13];
  const float* th2   = (const float*)d_in[14];
  const float* b2    = (const float*)d_in[15];
  const float* out_w = (const float*)d_in[16];
  const float* out_b = (const float*)d_in[17];

  float* logits_out = (float*)d_out;                 // [20000][2]
  float* gate_out   = logits_out + (size_t)NN * 2;   // [20000][128]

  char* p = (char*)d_ws;
  auto alloc = [&](size_t bytes) { char* r = p; p += (bytes + 255) & ~(size_t)255; return r; };
  float* Dv   = (float*)alloc((size_t)NN * 4);
  float* De   = (float*)alloc((size_t)NE * 4);
  float* isd  = (float*)alloc((size_t)NN * 4);
  float* es   = (float*)alloc((size_t)NE * 4);
  bf16_t* cat   = (bf16_t*)alloc((size_t)NN * 256 * 2);
  bf16_t* hid1  = (bf16_t*)alloc((size_t)NN * 256 * 2);
  bf16_t* fusedb= (bf16_t*)alloc((size_t)NN * 128 * 2);
  bf16_t* Yf    = (bf16_t*)alloc((size_t)16 * 640 * 512 * 2);   // 10.49 MB
  bf16_t* Hef   = (bf16_t*)alloc((size_t)16 * 128 * 512 * 2);   // 2.1 MB
  bf16_t* h     = (bf16_t*)alloc((size_t)NN * 256 * 2);
  bf16_t* pbuf  = (bf16_t*)alloc((size_t)AT_S * 256 * 4096 * 2); // 33.5 MB
  bf16_t* Hb    = (bf16_t*)alloc((size_t)NNP * NE * 2);
  bf16_t* psi_wt = (bf16_t*)alloc(65536 * 2);
  bf16_t* phi_wt = (bf16_t*)alloc(32768 * 2);
  bf16_t* g1_wt  = (bf16_t*)alloc(65536 * 2);
  bf16_t* g2_wt  = (bf16_t*)alloc(32768 * 2);
  bf16_t* th1_wt = (bf16_t*)alloc(32768 * 2);
  bf16_t* th2_wt = (bf16_t*)alloc(65536 * 2);

  hipMemsetAsync(Dv, 0, ((char*)isd - (char*)Dv), stream);

  cvtw_kern<<<1152, 256, 0, stream>>>(psi_w, phi_w, g1_w, g2_w, th1, th2,
                                      psi_wt, phi_wt, g1_wt, g2_wt, th1_wt, th2_wt);
  stats_cvt_kern<<<dim3(64, 160), 256, 0, stream>>>(H, w, Dv, De, Hb);
  finalize_kern<<<79, 256, 0, stream>>>(Dv, De, w, isd, es);

  // front-end MLP chain
  gemm_node_kern<true,  EPI_CAT ><<<dim3(625, 1), 256, 0, stream>>>(x, 512, psi_wt, 512, psi_b, nullptr, cat,       256, nullptr, nullptr);
  gemm_node_kern<true,  EPI_CAT ><<<dim3(625, 1), 256, 0, stream>>>(z, 256, phi_wt, 256, phi_b, nullptr, cat + 128, 256, nullptr, nullptr);
  gemm_node_kern<false, EPI_RELU><<<dim3(625, 2), 256, 0, stream>>>(cat, 256, g1_wt, 256, g1_b, nullptr, hid1, 256, nullptr, nullptr);
  gemm_node_kern<false, EPI_GATE><<<dim3(625, 1), 256, 0, stream>>>(hid1, 256, g2_wt, 256, g2_b, gate_out, fusedb, 128, cat, nullptr);

  // hconv 1
  gemm_node_kern<false, EPI_Y><<<dim3(640, 2), 256, 0, stream>>>(fusedb, 128, th1_wt, 128, nullptr, nullptr, Yf, 0, nullptr, isd);
  at_gemm_kern<<<dim3(32, AT_S), 512, 0, stream>>>(Hb, Yf, pbuf);
  reduce_he<<<1024, 256, 0, stream>>>(pbuf, es, Hef);
  out_gemm_kern<<<256, 512, 0, stream>>>(Hef, Hb, isd, b1, h);

  // hconv 2
  gemm_node_kern<false, EPI_Y><<<dim3(640, 2), 256, 0, stream>>>(h, 256, th2_wt, 256, nullptr, nullptr, Yf, 0, nullptr, isd);
  at_gemm_kern<<<dim3(32, AT_S), 512, 0, stream>>>(Hb, Yf, pbuf);
  reduce_he<<<1024, 256, 0, stream>>>(pbuf, es, Hef);
  out_gemm_kern<<<256, 512, 0, stream>>>(Hef, Hb, isd, b2, h);

  logits_kern<<<79, 256, 0, stream>>>(h, out_w, out_b, logits_out);
  (void)in_sizes; (void)n_in; (void)out_size; (void)ws_size;
}

// Round 6
// 771.320 us; speedup vs baseline: 1.7420x; 1.0548x over previous
//
#include <hip/hip_runtime.h>
#include <hip/hip_bf16.h>

// DF-HGNN fused pipeline v6: atomic-free stats pass (partial buffers),
// logits fused into conv-2 out_gemm epilogue.
// N=20000, E=4096, IN=512, DET=256, HID=256, HALF=128, OUT=2.

typedef __bf16 bf16_t;
typedef __attribute__((ext_vector_type(8))) __bf16 bf16x8;
typedef __attribute__((ext_vector_type(4))) __bf16 bf16x4;
typedef __attribute__((ext_vector_type(4))) float f32x4;

#define NN 20000
#define NE 4096
#define NNP 20480           // 640*32 padded node extent (zero rows >= NN)
#define AT_S 16             // n-split for H^T @ Y (32 e-blocks x 16 = 512 = 2/CU)
#define NEB 64              // e-blocks in stats grid
#define NNB 160             // n-blocks in stats grid
// Fragment-major layouts:
//  Yf  [fblk 16][nblk 640][lane 64][8]  : value(f,n) at lane=((n&31)>>3)*16+(f&15), j=n&7
//  Hef [fblk 16][eblk 128][lane 64][8]  : value(f,e) same scheme with k=e
//  part[s][tile=eblk16*16+fblk][lane 64][4] : D-frag dump; e=eblk16*16+lq*4+r, f=fblk*16+lr

__device__ __forceinline__ f32x4 mfma16(bf16x8 a, bf16x8 b, f32x4 c) {
  return __builtin_amdgcn_mfma_f32_16x16x32_bf16(a, b, c, 0, 0, 0);
}

// ---------------- fused stats + bf16 cast: Dvp, Dep, Hb[n][e] --------------
// grid (64 e-blocks, 160 n-blocks), tile 128n x 64e. No atomics: per-block
// partials -> Dvp[eb][n], Dep[nb][e], reduced in finalize_kern.
__global__ __launch_bounds__(256) void stats_cvt_kern(const float* __restrict__ H,
                                                      const float* __restrict__ w,
                                                      float* __restrict__ Dvp,
                                                      float* __restrict__ Dep,
                                                      bf16_t* __restrict__ Hb) {
  __shared__ bf16_t tile[128 * 72];
  __shared__ float colp[8][64];
  int t = threadIdx.x;
  long e0 = (long)blockIdx.x * 64;
  long n0 = (long)blockIdx.y * 128;
  int r = t >> 1, ch = t & 1;
  long row = n0 + r;
  float dvp = 0.f;
  bf16_t* dstl = tile + r * 72 + ch * 32;
  bf16x8 loc[4];
  if (row < NN) {
    const float* hp = H + row * NE + e0 + ch * 32;
    const float* wp = w + e0 + ch * 32;
    #pragma unroll
    for (int q = 0; q < 4; ++q) {
      f32x4 u0 = *(const f32x4*)(hp + q * 8);
      f32x4 u1 = *(const f32x4*)(hp + q * 8 + 4);
      f32x4 w0 = *(const f32x4*)(wp + q * 8);
      f32x4 w1 = *(const f32x4*)(wp + q * 8 + 4);
      bf16x8 b;
      #pragma unroll
      for (int j = 0; j < 4; ++j) { b[j] = (__bf16)u0[j]; b[4 + j] = (__bf16)u1[j]; }
      loc[q] = b;
      dvp += u0[0]*w0[0] + u0[1]*w0[1] + u0[2]*w0[2] + u0[3]*w0[3]
           + u1[0]*w1[0] + u1[1]*w1[1] + u1[2]*w1[2] + u1[3]*w1[3];
    }
  } else {
    bf16x8 zz;
    #pragma unroll
    for (int j = 0; j < 8; ++j) zz[j] = (__bf16)0.f;
    #pragma unroll
    for (int q = 0; q < 4; ++q) loc[q] = zz;
  }
  #pragma unroll
  for (int q = 0; q < 4; ++q) *(bf16x8*)(dstl + q * 8) = loc[q];
  {
    bf16_t* hb = Hb + row * NE + e0 + ch * 32;
    #pragma unroll
    for (int q = 0; q < 4; ++q) *(bf16x8*)(hb + q * 8) = loc[q];
  }
  dvp += __shfl_xor(dvp, 1);
  if (ch == 0) Dvp[(long)blockIdx.x * NNP + row] = dvp;   // rows >= NN write 0
  __syncthreads();
  {
    int c2 = t & 31, rg = t >> 5;
    float s0 = 0.f, s1 = 0.f;
    #pragma unroll
    for (int j = 0; j < 16; ++j) {
      unsigned u = *(const unsigned*)(tile + (rg * 16 + j) * 72 + c2 * 2);
      s0 += __uint_as_float(u << 16);
      s1 += __uint_as_float(u & 0xffff0000u);
    }
    colp[rg][c2 * 2] = s0;
    colp[rg][c2 * 2 + 1] = s1;
  }
  __syncthreads();
  if (t < 64) {
    float s = 0.f;
    #pragma unroll
    for (int j = 0; j < 8; ++j) s += colp[j][t];
    Dep[(long)blockIdx.y * NE + e0 + t] = s;
  }
}

// isd[n] = rsqrt(max(sum_b Dvp, eps));  es[e] = w/max(sum_b Dep, eps)
__global__ __launch_bounds__(256) void finalize_kern(const float* __restrict__ Dvp,
                                                     const float* __restrict__ Dep,
                                                     const float* __restrict__ w,
                                                     float* __restrict__ isd,
                                                     float* __restrict__ es) {
  int t = blockIdx.x * 256 + threadIdx.x;
  if (t < NN) {
    float s = 0.f;
    #pragma unroll 8
    for (int b = 0; b < NEB; ++b) s += Dvp[(long)b * NNP + t];
    isd[t] = rsqrtf(fmaxf(s, 1e-6f));
  }
  if (t < NE) {
    float s = 0.f;
    #pragma unroll 8
    for (int b = 0; b < NNB; ++b) s += Dep[(long)b * NE + t];
    es[t] = w[t] / fmaxf(s, 1e-6f);
  }
}

// -------------------------------------------- weight transpose+cast (tiny)
__global__ void cvtw_kern(const float* __restrict__ psi, const float* __restrict__ phi,
                          const float* __restrict__ g1,  const float* __restrict__ g2,
                          const float* __restrict__ th1, const float* __restrict__ th2,
                          bf16_t* dpsi, bf16_t* dphi, bf16_t* dg1, bf16_t* dg2,
                          bf16_t* dth1, bf16_t* dth2) {
  int t = blockIdx.x * 256 + threadIdx.x;
  if (t < 65536) {
    int nc = t >> 9, k = t & 511; dpsi[t] = (__bf16)psi[k * 128 + nc];
  } else if (t < 98304) {
    int i = t - 65536; int nc = i >> 8, k = i & 255; dphi[i] = (__bf16)phi[k * 128 + nc];
  } else if (t < 163840) {
    int i = t - 98304; int nc = i >> 8, k = i & 255; dg1[i] = (__bf16)g1[k * 256 + nc];
  } else if (t < 196608) {
    int i = t - 163840; int nc = i >> 8, k = i & 255; dg2[i] = (__bf16)g2[k * 128 + nc];
  } else if (t < 229376) {
    int i = t - 196608; int nc = i >> 7, k = i & 127; dth1[i] = (__bf16)th1[k * 256 + nc];
  } else if (t < 294912) {
    int i = t - 229376; int nc = i >> 8, k = i & 255; dth2[i] = (__bf16)th2[k * 256 + nc];
  }
}

// --------------------------------------------------- node-feature GEMMs
enum { EPI_CAT = 0, EPI_RELU = 1, EPI_GATE = 2, EPI_Y = 3 };

template<bool AF32, int EPI>
__global__ __launch_bounds__(256) void gemm_node_kern(
    const void* __restrict__ Av, int lda, const bf16_t* __restrict__ Bt, int K,
    const float* __restrict__ bias, float* __restrict__ gate_out,
    bf16_t* __restrict__ dst, int ldc, const bf16_t* __restrict__ cat,
    const float* __restrict__ isd) {
  int tid = threadIdx.x, l = tid & 63, wv = tid >> 6;
  int lr = l & 15, lq = l >> 4;
  int hm = wv >> 1;
  int mo = blockIdx.x * 32 + hm * 16;
  int no = blockIdx.y * 128 + (wv & 1) * 64;
  f32x4 acc[4] = {};
  for (int k0 = 0; k0 < K; k0 += 32) {
    int row = mo + lr;
    bf16x8 a;
    if (row < NN) {
      if constexpr (AF32) {
        const float* ap = (const float*)Av + (long)row * lda + k0 + lq * 8;
        f32x4 u0 = *(const f32x4*)ap, u1 = *(const f32x4*)(ap + 4);
        #pragma unroll
        for (int j = 0; j < 4; ++j) { a[j] = (__bf16)u0[j]; a[j + 4] = (__bf16)u1[j]; }
      } else {
        a = *(const bf16x8*)((const bf16_t*)Av + (long)row * lda + k0 + lq * 8);
      }
    } else {
      #pragma unroll
      for (int j = 0; j < 8; ++j) a[j] = (__bf16)0.f;
    }
    #pragma unroll
    for (int ni = 0; ni < 4; ++ni) {
      bf16x8 b = *(const bf16x8*)(Bt + (long)(no + ni * 16 + lr) * K + k0 + lq * 8);
      acc[ni] = mfma16(a, b, acc[ni]);
    }
  }
  #pragma unroll
  for (int ni = 0; ni < 4; ++ni) {
    int colf = no + ni * 16 + lr;
    int rb = mo + lq * 4;
    f32x4 v = acc[ni];
    if constexpr (EPI == EPI_CAT) {
      float bs = bias[colf];
      for (int r = 0; r < 4; ++r) { int n = rb + r;
        if (n < NN) dst[(long)n * ldc + colf] = (__bf16)(v[r] + bs); }
    } else if constexpr (EPI == EPI_RELU) {
      float bs = bias[colf];
      for (int r = 0; r < 4; ++r) { int n = rb + r;
        if (n < NN) { float xx = v[r] + bs; dst[(long)n * ldc + colf] = (__bf16)(xx > 0.f ? xx : 0.f); } }
    } else if constexpr (EPI == EPI_GATE) {
      float bs = bias[colf];
      for (int r = 0; r < 4; ++r) {
        int n = rb + r;
        if (n < NN) {
          float g = 1.f / (1.f + __expf(-(v[r] + bs)));
          gate_out[(long)n * 128 + colf] = g;
          float px = (float)cat[(long)n * 256 + colf];
          float pz = (float)cat[(long)n * 256 + 128 + colf];
          dst[(long)n * 128 + colf] = (__bf16)(g * pz + (1.f - g) * px);
        }
      }
    } else {  // EPI_Y: fragment-major Yf, coalesced 8B store per ni
      int fblk = (no >> 4) + ni;
      int nblk = blockIdx.x;
      int lanep = (hm * 2 + (lq >> 1)) * 16 + lr;
      bf16x4 pk;
      for (int r = 0; r < 4; ++r) {
        int nr = rb + r;
        float sc = (nr < NN) ? isd[nr] : 0.f;
        pk[r] = (__bf16)(v[r] * sc);
      }
      *(bf16x4*)(dst + (((long)fblk * 640 + nblk) * 64 + lanep) * 8 + (lq & 1) * 4) = pk;
    }
  }
}

// --------------------------------------------- He partials: fragment-major
// He[e][f] = sum_n Hb[n][e]*Y[f][n]. 8 waves, block tile 128e x 256f,
// wave tile 64e x 64f. BK=64 per barrier pair, LDS transpose + reg prefetch.
__global__ __launch_bounds__(512) void at_gemm_kern(const bf16_t* __restrict__ Hb,
                                                    const bf16_t* __restrict__ Yf,
                                                    bf16_t* __restrict__ part) {
  __shared__ bf16_t T[128 * 72];       // [e_local][64 n + pad]
  int t = threadIdx.x, l = t & 63, wv = t >> 6;
  int lr = l & 15, lq = l >> 4;
  int eh = wv >> 2, fq = wv & 3;       // wave: e-half, f-quarter
  int e0 = blockIdx.x * 128;
  int s0 = blockIdx.y * 20, s1 = s0 + 20;   // BK64 steps
  int rp = t >> 4;                     // row-pair 0..31 (64 rows)
  int ck = t & 15;                     // 8-e column chunk
  f32x4 acc[4][4] = {};
  const bf16_t* src = Hb + ((long)s0 * 64 + 2 * rp) * NE + e0 + ck * 8;
  bf16x8 ra = *(const bf16x8*)src;
  bf16x8 rb = *(const bf16x8*)(src + NE);
  for (int s = s0; s < s1; ++s) {
    __syncthreads();
    #pragma unroll
    for (int j = 0; j < 8; ++j) {
      int jj = (j + ck) & 7;           // rotation -> 32 banks, exact 2-way (free)
      int el = ck * 8 + jj;
      unsigned lo = (unsigned)__builtin_bit_cast(unsigned short, (__bf16)ra[jj]);
      unsigned hi = (unsigned)__builtin_bit_cast(unsigned short, (__bf16)rb[jj]);
      *(unsigned*)(T + el * 72 + rp * 2) = lo | (hi << 16);
    }
    __syncthreads();
    if (s + 1 < s1) {                  // prefetch next stripe under MFMA
      src += 64 * (long)NE;
      ra = *(const bf16x8*)src;
      rb = *(const bf16x8*)(src + NE);
    }
    #pragma unroll
    for (int k32 = 0; k32 < 2; ++k32) {
      bf16x8 a[4], b[4];
      #pragma unroll
      for (int ni = 0; ni < 4; ++ni)
        a[ni] = *(const bf16x8*)(T + (eh * 64 + ni * 16 + lr) * 72 + k32 * 32 + lq * 8);
      const bf16_t* bp = Yf + ((long)(s * 2 + k32) * 64 + l) * 8;
      #pragma unroll
      for (int ni = 0; ni < 4; ++ni)
        b[ni] = *(const bf16x8*)(bp + (long)(fq * 4 + ni) * 640 * 512);
      #pragma unroll
      for (int ae = 0; ae < 4; ++ae)
        #pragma unroll
        for (int bf = 0; bf < 4; ++bf)
          acc[ae][bf] = mfma16(a[ae], b[bf], acc[ae][bf]);
    }
  }
  bf16_t* pp = part + (long)blockIdx.y * (256 * 4096);
  #pragma unroll
  for (int ae = 0; ae < 4; ++ae) {
    int eblk16 = (e0 >> 4) + eh * 4 + ae;
    #pragma unroll
    for (int bf = 0; bf < 4; ++bf) {
      int fblk = fq * 4 + bf;
      f32x4 v = acc[ae][bf];
      bf16x4 pk;
      for (int r = 0; r < 4; ++r) pk[r] = (__bf16)v[r];
      *(bf16x4*)(pp + (((long)eblk16 * 16 + fblk) * 64 + l) * 4) = pk;
    }
  }
}

// Hef[f][e] (fragment-major) = es[e] * sum_s part[s][...]
__global__ __launch_bounds__(256) void reduce_he(const bf16_t* __restrict__ part,
                                                 const float* __restrict__ es,
                                                 bf16_t* __restrict__ Hef) {
  int u = blockIdx.x * 256 + threadIdx.x;      // 0..262143
  int lane = u & 63, tile = u >> 6;
  int fblk = tile & 15, eblk16 = tile >> 4;
  int lr = lane & 15, lq = lane >> 4;
  int e_base = eblk16 * 16 + lq * 4;
  float a0 = 0.f, a1 = 0.f, a2 = 0.f, a3 = 0.f;
  #pragma unroll
  for (int s = 0; s < AT_S; ++s) {
    bf16x4 v = *(const bf16x4*)(part + (long)s * (256 * 4096) + (long)u * 4);
    a0 += (float)v[0]; a1 += (float)v[1]; a2 += (float)v[2]; a3 += (float)v[3];
  }
  f32x4 e4 = *(const f32x4*)(es + e_base);
  bf16x4 pk;
  pk[0] = (__bf16)(a0 * e4[0]); pk[1] = (__bf16)(a1 * e4[1]);
  pk[2] = (__bf16)(a2 * e4[2]); pk[3] = (__bf16)(a3 * e4[3]);
  int eblk32 = eblk16 >> 1;
  int lanep = ((eblk16 & 1) * 2 + (lq >> 1)) * 16 + lr;
  long slot = (((long)fblk * 128 + eblk32) * 64 + lanep) * 8 + (lq & 1) * 4;
  *(bf16x4*)(Hef + slot) = pk;
}

// -------- conv out: h[n][f] = relu(isd[n]*(Hb[n]@He) + bias) --------------
// FLOG=1: fuse logits = h @ out_w + out_b, skip writing h.
template<int FLOG>
__global__ __launch_bounds__(512) void out_gemm_kern(const bf16_t* __restrict__ Hef,
                                                     const bf16_t* __restrict__ Hb,
                                                     const float* __restrict__ isd,
                                                     const float* __restrict__ bias,
                                                     bf16_t* __restrict__ h,
                                                     const float* __restrict__ ow,
                                                     const float* __restrict__ ob,
                                                     float* __restrict__ out) {
  __shared__ float lgp[8][80][2];
  int t = threadIdx.x, l = t & 63, wv = t >> 6;
  int lr = l & 15, lq = l >> 4;
  long r0 = (long)blockIdx.x * 80;
  int fo = wv * 32;
  f32x4 acc[5][2] = {};
  const bf16_t* ap = Hb + (r0 + lr) * (long)NE + lq * 8;
  const bf16_t* bp = Hef + (long)(wv * 2) * 65536 + l * 8;
  bf16x8 a[5], b[2];
  #pragma unroll
  for (int mi = 0; mi < 5; ++mi) a[mi] = *(const bf16x8*)(ap + (long)mi * 16 * NE);
  b[0] = *(const bf16x8*)(bp);
  b[1] = *(const bf16x8*)(bp + 65536);
  for (int k0 = 32; k0 < NE; k0 += 32) {
    int eblk = k0 >> 5;
    bf16x8 an[5], bn[2];
    #pragma unroll
    for (int mi = 0; mi < 5; ++mi) an[mi] = *(const bf16x8*)(ap + (long)mi * 16 * NE + k0);
    bn[0] = *(const bf16x8*)(bp + eblk * 512);
    bn[1] = *(const bf16x8*)(bp + 65536 + eblk * 512);
    #pragma unroll
    for (int mi = 0; mi < 5; ++mi) {
      acc[mi][0] = mfma16(a[mi], b[0], acc[mi][0]);
      acc[mi][1] = mfma16(a[mi], b[1], acc[mi][1]);
    }
    #pragma unroll
    for (int mi = 0; mi < 5; ++mi) a[mi] = an[mi];
    b[0] = bn[0]; b[1] = bn[1];
  }
  #pragma unroll
  for (int mi = 0; mi < 5; ++mi) {
    acc[mi][0] = mfma16(a[mi], b[0], acc[mi][0]);
    acc[mi][1] = mfma16(a[mi], b[1], acc[mi][1]);
  }
  #pragma unroll
  for (int mi = 0; mi < 5; ++mi) {
    long nb = r0 + mi * 16 + lq * 4;
    #pragma unroll
    for (int r = 0; r < 4; ++r) {
      long n = nb + r;
      float sd = (n < NN) ? isd[n] : 0.f;
      float a0 = 0.f, a1 = 0.f;
      #pragma unroll
      for (int ni = 0; ni < 2; ++ni) {
        int f = fo + ni * 16 + lr;
        float vv = acc[mi][ni][r] * sd + bias[f];
        vv = vv > 0.f ? vv : 0.f;
        if constexpr (!FLOG) {
          if (n < NN) h[n * 256 + f] = (__bf16)vv;
        } else {
          a0 += vv * ow[f * 2];
          a1 += vv * ow[f * 2 + 1];
        }
      }
      if constexpr (FLOG) {
        #pragma unroll
        for (int m = 1; m < 16; m <<= 1) { a0 += __shfl_xor(a0, m); a1 += __shfl_xor(a1, m); }
        if (lr == 0) {
          int rowl = mi * 16 + lq * 4 + r;
          lgp[wv][rowl][0] = a0;
          lgp[wv][rowl][1] = a1;
        }
      }
    }
  }
  if constexpr (FLOG) {
    __syncthreads();
    if (t < 80) {
      float s0 = 0.f, s1 = 0.f;
      #pragma unroll
      for (int wvi = 0; wvi < 8; ++wvi) { s0 += lgp[wvi][t][0]; s1 += lgp[wvi][t][1]; }
      long n = r0 + t;
      if (n < NN) {
        out[n * 2]     = s0 + ob[0];
        out[n * 2 + 1] = s1 + ob[1];
      }
    }
  }
}

// ============================================================== launcher
extern "C" void kernel_launch(void* const* d_in, const int* in_sizes, int n_in,
                              void* d_out, int out_size, void* d_ws, size_t ws_size,
                              hipStream_t stream) {
  const float* x    = (const float*)d_in[0];
  const float* z    = (const float*)d_in[1];
  const float* H    = (const float*)d_in[2];
  const float* w    = (const float*)d_in[3];
  const float* psi_w = (const float*)d_in[4];
  const float* psi_b = (const float*)d_in[5];
  const float* phi_w = (const float*)d_in[6];
  const float* phi_b = (const float*)d_in[7];
  const float* g1_w  = (const float*)d_in[8];
  const float* g1_b  = (const float*)d_in[9];
  const float* g2_w  = (const float*)d_in[10];
  const float* g2_b  = (const float*)d_in[11];
  const float* th1   = (const float*)d_in[12];
  const float* b1    = (const float*)d_in[13];
  const float* th2   = (const float*)d_in[14];
  const float* b2    = (const float*)d_in[15];
  const float* out_w = (const float*)d_in[16];
  const float* out_b = (const float*)d_in[17];

  float* logits_out = (float*)d_out;                 // [20000][2]
  float* gate_out   = logits_out + (size_t)NN * 2;   // [20000][128]

  char* p = (char*)d_ws;
  auto alloc = [&](size_t bytes) { char* r = p; p += (bytes + 255) & ~(size_t)255; return r; };
  float* Dvp  = (float*)alloc((size_t)NEB * NNP * 4);   // 5.24 MB
  float* Dep  = (float*)alloc((size_t)NNB * NE * 4);    // 2.62 MB
  float* isd  = (float*)alloc((size_t)NN * 4);
  float* es   = (float*)alloc((size_t)NE * 4);
  bf16_t* cat   = (bf16_t*)alloc((size_t)NN * 256 * 2);
  bf16_t* hid1  = (bf16_t*)alloc((size_t)NN * 256 * 2);
  bf16_t* fusedb= (bf16_t*)alloc((size_t)NN * 128 * 2);
  bf16_t* Yf    = (bf16_t*)alloc((size_t)16 * 640 * 512 * 2);   // 10.49 MB
  bf16_t* Hef   = (bf16_t*)alloc((size_t)16 * 128 * 512 * 2);   // 2.1 MB
  bf16_t* h     = (bf16_t*)alloc((size_t)NN * 256 * 2);
  bf16_t* pbuf  = (bf16_t*)alloc((size_t)AT_S * 256 * 4096 * 2); // 33.5 MB
  bf16_t* Hb    = (bf16_t*)alloc((size_t)NNP * NE * 2);
  bf16_t* psi_wt = (bf16_t*)alloc(65536 * 2);
  bf16_t* phi_wt = (bf16_t*)alloc(32768 * 2);
  bf16_t* g1_wt  = (bf16_t*)alloc(65536 * 2);
  bf16_t* g2_wt  = (bf16_t*)alloc(32768 * 2);
  bf16_t* th1_wt = (bf16_t*)alloc(32768 * 2);
  bf16_t* th2_wt = (bf16_t*)alloc(65536 * 2);

  cvtw_kern<<<1152, 256, 0, stream>>>(psi_w, phi_w, g1_w, g2_w, th1, th2,
                                      psi_wt, phi_wt, g1_wt, g2_wt, th1_wt, th2_wt);
  stats_cvt_kern<<<dim3(NEB, NNB), 256, 0, stream>>>(H, w, Dvp, Dep, Hb);
  finalize_kern<<<79, 256, 0, stream>>>(Dvp, Dep, w, isd, es);

  // front-end MLP chain
  gemm_node_kern<true,  EPI_CAT ><<<dim3(625, 1), 256, 0, stream>>>(x, 512, psi_wt, 512, psi_b, nullptr, cat,       256, nullptr, nullptr);
  gemm_node_kern<true,  EPI_CAT ><<<dim3(625, 1), 256, 0, stream>>>(z, 256, phi_wt, 256, phi_b, nullptr, cat + 128, 256, nullptr, nullptr);
  gemm_node_kern<false, EPI_RELU><<<dim3(625, 2), 256, 0, stream>>>(cat, 256, g1_wt, 256, g1_b, nullptr, hid1, 256, nullptr, nullptr);
  gemm_node_kern<false, EPI_GATE><<<dim3(625, 1), 256, 0, stream>>>(hid1, 256, g2_wt, 256, g2_b, gate_out, fusedb, 128, cat, nullptr);

  // hconv 1
  gemm_node_kern<false, EPI_Y><<<dim3(640, 2), 256, 0, stream>>>(fusedb, 128, th1_wt, 128, nullptr, nullptr, Yf, 0, nullptr, isd);
  at_gemm_kern<<<dim3(32, AT_S), 512, 0, stream>>>(Hb, Yf, pbuf);
  reduce_he<<<1024, 256, 0, stream>>>(pbuf, es, Hef);
  out_gemm_kern<0><<<256, 512, 0, stream>>>(Hef, Hb, isd, b1, h, nullptr, nullptr, nullptr);

  // hconv 2 (logits fused into out_gemm epilogue)
  gemm_node_kern<false, EPI_Y><<<dim3(640, 2), 256, 0, stream>>>(h, 256, th2_wt, 256, nullptr, nullptr, Yf, 0, nullptr, isd);
  at_gemm_kern<<<dim3(32, AT_S), 512, 0, stream>>>(Hb, Yf, pbuf);
  reduce_he<<<1024, 256, 0, stream>>>(pbuf, es, Hef);
  out_gemm_kern<1><<<256, 512, 0, stream>>>(Hef, Hb, isd, b2, nullptr, out_w, out_b, logits_out);

  (void)in_sizes; (void)n_in; (void)out_size; (void)ws_size;
}

// Round 7
// 739.827 us; speedup vs baseline: 1.8162x; 1.0426x over previous
//
#include <hip/hip_runtime.h>
#include <hip/hip_bf16.h>

// DF-HGNN fused pipeline v7: stats_cvt rewritten for wave-contiguous 1KB
// loads (lane = column quad). Rest identical to v6.
// N=20000, E=4096, IN=512, DET=256, HID=256, HALF=128, OUT=2.

typedef __bf16 bf16_t;
typedef __attribute__((ext_vector_type(8))) __bf16 bf16x8;
typedef __attribute__((ext_vector_type(4))) __bf16 bf16x4;
typedef __attribute__((ext_vector_type(4))) float f32x4;

#define NN 20000
#define NE 4096
#define NNP 20480           // 640*32 padded node extent (zero rows >= NN)
#define AT_S 16             // n-split for H^T @ Y (32 e-blocks x 16 = 512 = 2/CU)
#define NEB 16              // e-blocks in stats grid (256 cols each)
#define NNB 160             // n-blocks in stats grid (128 rows each)
// Fragment-major layouts:
//  Yf  [fblk 16][nblk 640][lane 64][8]  : value(f,n) at lane=((n&31)>>3)*16+(f&15), j=n&7
//  Hef [fblk 16][eblk 128][lane 64][8]  : value(f,e) same scheme with k=e
//  part[s][tile=eblk16*16+fblk][lane 64][4] : D-frag dump; e=eblk16*16+lq*4+r, f=fblk*16+lr

__device__ __forceinline__ f32x4 mfma16(bf16x8 a, bf16x8 b, f32x4 c) {
  return __builtin_amdgcn_mfma_f32_16x16x32_bf16(a, b, c, 0, 0, 0);
}

// ---------------- fused stats + bf16 cast: Dvp, Dep, Hb[n][e] --------------
// grid (16 e-blocks x 256 cols, 160 n-blocks x 128 rows). Lane l owns cols
// e0+4l..4l+3: every global load = 1KB wave-contiguous, store = 512B.
__global__ __launch_bounds__(256) void stats_cvt_kern(const float* __restrict__ H,
                                                      const float* __restrict__ w,
                                                      float* __restrict__ Dvp,
                                                      float* __restrict__ Dep,
                                                      bf16_t* __restrict__ Hb) {
  __shared__ float dvl[128];
  __shared__ float deP[4][256];
  int t = threadIdx.x, l = t & 63, wv = t >> 6;
  long e0 = (long)blockIdx.x * 256;
  long n0 = (long)blockIdx.y * 128;
  f32x4 w4 = *(const f32x4*)(w + e0 + l * 4);
  f32x4 de; de[0] = de[1] = de[2] = de[3] = 0.f;
  #pragma unroll 4
  for (int i = 0; i < 32; ++i) {
    long row = n0 + wv * 32 + i;
    float s;
    if (row < NN) {
      f32x4 u = *(const f32x4*)(H + row * NE + e0 + l * 4);
      bf16x4 pk;
      #pragma unroll
      for (int j = 0; j < 4; ++j) pk[j] = (__bf16)u[j];
      *(bf16x4*)(Hb + row * NE + e0 + l * 4) = pk;
      de += u;
      s = u[0] * w4[0] + u[1] * w4[1] + u[2] * w4[2] + u[3] * w4[3];
    } else {
      bf16x4 z;
      #pragma unroll
      for (int j = 0; j < 4; ++j) z[j] = (__bf16)0.f;
      *(bf16x4*)(Hb + row * NE + e0 + l * 4) = z;
      s = 0.f;
    }
    #pragma unroll
    for (int m = 1; m < 64; m <<= 1) s += __shfl_xor(s, m);
    if (l == 0) dvl[wv * 32 + i] = s;
  }
  *(f32x4*)(&deP[wv][l * 4]) = de;
  __syncthreads();
  if (t < 128) Dvp[(long)blockIdx.x * NNP + n0 + t] = dvl[t];
  {
    float s = deP[0][t] + deP[1][t] + deP[2][t] + deP[3][t];
    Dep[(long)blockIdx.y * NE + e0 + t] = s;
  }
}

// isd[n] = rsqrt(max(sum_b Dvp, eps));  es[e] = w/max(sum_b Dep, eps)
__global__ __launch_bounds__(256) void finalize_kern(const float* __restrict__ Dvp,
                                                     const float* __restrict__ Dep,
                                                     const float* __restrict__ w,
                                                     float* __restrict__ isd,
                                                     float* __restrict__ es) {
  int t = blockIdx.x * 256 + threadIdx.x;
  if (t < NN) {
    float s = 0.f;
    #pragma unroll 8
    for (int b = 0; b < NEB; ++b) s += Dvp[(long)b * NNP + t];
    isd[t] = rsqrtf(fmaxf(s, 1e-6f));
  }
  if (t < NE) {
    float s = 0.f;
    #pragma unroll 8
    for (int b = 0; b < NNB; ++b) s += Dep[(long)b * NE + t];
    es[t] = w[t] / fmaxf(s, 1e-6f);
  }
}

// -------------------------------------------- weight transpose+cast (tiny)
__global__ void cvtw_kern(const float* __restrict__ psi, const float* __restrict__ phi,
                          const float* __restrict__ g1,  const float* __restrict__ g2,
                          const float* __restrict__ th1, const float* __restrict__ th2,
                          bf16_t* dpsi, bf16_t* dphi, bf16_t* dg1, bf16_t* dg2,
                          bf16_t* dth1, bf16_t* dth2) {
  int t = blockIdx.x * 256 + threadIdx.x;
  if (t < 65536) {
    int nc = t >> 9, k = t & 511; dpsi[t] = (__bf16)psi[k * 128 + nc];
  } else if (t < 98304) {
    int i = t - 65536; int nc = i >> 8, k = i & 255; dphi[i] = (__bf16)phi[k * 128 + nc];
  } else if (t < 163840) {
    int i = t - 98304; int nc = i >> 8, k = i & 255; dg1[i] = (__bf16)g1[k * 256 + nc];
  } else if (t < 196608) {
    int i = t - 163840; int nc = i >> 8, k = i & 255; dg2[i] = (__bf16)g2[k * 128 + nc];
  } else if (t < 229376) {
    int i = t - 196608; int nc = i >> 7, k = i & 127; dth1[i] = (__bf16)th1[k * 256 + nc];
  } else if (t < 294912) {
    int i = t - 229376; int nc = i >> 8, k = i & 255; dth2[i] = (__bf16)th2[k * 256 + nc];
  }
}

// --------------------------------------------------- node-feature GEMMs
enum { EPI_CAT = 0, EPI_RELU = 1, EPI_GATE = 2, EPI_Y = 3 };

template<bool AF32, int EPI>
__global__ __launch_bounds__(256) void gemm_node_kern(
    const void* __restrict__ Av, int lda, const bf16_t* __restrict__ Bt, int K,
    const float* __restrict__ bias, float* __restrict__ gate_out,
    bf16_t* __restrict__ dst, int ldc, const bf16_t* __restrict__ cat,
    const float* __restrict__ isd) {
  int tid = threadIdx.x, l = tid & 63, wv = tid >> 6;
  int lr = l & 15, lq = l >> 4;
  int hm = wv >> 1;
  int mo = blockIdx.x * 32 + hm * 16;
  int no = blockIdx.y * 128 + (wv & 1) * 64;
  f32x4 acc[4] = {};
  for (int k0 = 0; k0 < K; k0 += 32) {
    int row = mo + lr;
    bf16x8 a;
    if (row < NN) {
      if constexpr (AF32) {
        const float* ap = (const float*)Av + (long)row * lda + k0 + lq * 8;
        f32x4 u0 = *(const f32x4*)ap, u1 = *(const f32x4*)(ap + 4);
        #pragma unroll
        for (int j = 0; j < 4; ++j) { a[j] = (__bf16)u0[j]; a[j + 4] = (__bf16)u1[j]; }
      } else {
        a = *(const bf16x8*)((const bf16_t*)Av + (long)row * lda + k0 + lq * 8);
      }
    } else {
      #pragma unroll
      for (int j = 0; j < 8; ++j) a[j] = (__bf16)0.f;
    }
    #pragma unroll
    for (int ni = 0; ni < 4; ++ni) {
      bf16x8 b = *(const bf16x8*)(Bt + (long)(no + ni * 16 + lr) * K + k0 + lq * 8);
      acc[ni] = mfma16(a, b, acc[ni]);
    }
  }
  #pragma unroll
  for (int ni = 0; ni < 4; ++ni) {
    int colf = no + ni * 16 + lr;
    int rb = mo + lq * 4;
    f32x4 v = acc[ni];
    if constexpr (EPI == EPI_CAT) {
      float bs = bias[colf];
      for (int r = 0; r < 4; ++r) { int n = rb + r;
        if (n < NN) dst[(long)n * ldc + colf] = (__bf16)(v[r] + bs); }
    } else if constexpr (EPI == EPI_RELU) {
      float bs = bias[colf];
      for (int r = 0; r < 4; ++r) { int n = rb + r;
        if (n < NN) { float xx = v[r] + bs; dst[(long)n * ldc + colf] = (__bf16)(xx > 0.f ? xx : 0.f); } }
    } else if constexpr (EPI == EPI_GATE) {
      float bs = bias[colf];
      for (int r = 0; r < 4; ++r) {
        int n = rb + r;
        if (n < NN) {
          float g = 1.f / (1.f + __expf(-(v[r] + bs)));
          gate_out[(long)n * 128 + colf] = g;
          float px = (float)cat[(long)n * 256 + colf];
          float pz = (float)cat[(long)n * 256 + 128 + colf];
          dst[(long)n * 128 + colf] = (__bf16)(g * pz + (1.f - g) * px);
        }
      }
    } else {  // EPI_Y: fragment-major Yf, coalesced 8B store per ni
      int fblk = (no >> 4) + ni;
      int nblk = blockIdx.x;
      int lanep = (hm * 2 + (lq >> 1)) * 16 + lr;
      bf16x4 pk;
      for (int r = 0; r < 4; ++r) {
        int nr = rb + r;
        float sc = (nr < NN) ? isd[nr] : 0.f;
        pk[r] = (__bf16)(v[r] * sc);
      }
      *(bf16x4*)(dst + (((long)fblk * 640 + nblk) * 64 + lanep) * 8 + (lq & 1) * 4) = pk;
    }
  }
}

// --------------------------------------------- He partials: fragment-major
// He[e][f] = sum_n Hb[n][e]*Y[f][n]. 8 waves, block tile 128e x 256f,
// wave tile 64e x 64f. BK=64 per barrier pair, LDS transpose + reg prefetch.
__global__ __launch_bounds__(512) void at_gemm_kern(const bf16_t* __restrict__ Hb,
                                                    const bf16_t* __restrict__ Yf,
                                                    bf16_t* __restrict__ part) {
  __shared__ bf16_t T[128 * 72];       // [e_local][64 n + pad]
  int t = threadIdx.x, l = t & 63, wv = t >> 6;
  int lr = l & 15, lq = l >> 4;
  int eh = wv >> 2, fq = wv & 3;       // wave: e-half, f-quarter
  int e0 = blockIdx.x * 128;
  int s0 = blockIdx.y * 20, s1 = s0 + 20;   // BK64 steps
  int rp = t >> 4;                     // row-pair 0..31 (64 rows)
  int ck = t & 15;                     // 8-e column chunk
  f32x4 acc[4][4] = {};
  const bf16_t* src = Hb + ((long)s0 * 64 + 2 * rp) * NE + e0 + ck * 8;
  bf16x8 ra = *(const bf16x8*)src;
  bf16x8 rb = *(const bf16x8*)(src + NE);
  for (int s = s0; s < s1; ++s) {
    __syncthreads();
    #pragma unroll
    for (int j = 0; j < 8; ++j) {
      int jj = (j + ck) & 7;           // rotation -> 32 banks, exact 2-way (free)
      int el = ck * 8 + jj;
      unsigned lo = (unsigned)__builtin_bit_cast(unsigned short, (__bf16)ra[jj]);
      unsigned hi = (unsigned)__builtin_bit_cast(unsigned short, (__bf16)rb[jj]);
      *(unsigned*)(T + el * 72 + rp * 2) = lo | (hi << 16);
    }
    __syncthreads();
    if (s + 1 < s1) {                  // prefetch next stripe under MFMA
      src += 64 * (long)NE;
      ra = *(const bf16x8*)src;
      rb = *(const bf16x8*)(src + NE);
    }
    #pragma unroll
    for (int k32 = 0; k32 < 2; ++k32) {
      bf16x8 a[4], b[4];
      #pragma unroll
      for (int ni = 0; ni < 4; ++ni)
        a[ni] = *(const bf16x8*)(T + (eh * 64 + ni * 16 + lr) * 72 + k32 * 32 + lq * 8);
      const bf16_t* bp = Yf + ((long)(s * 2 + k32) * 64 + l) * 8;
      #pragma unroll
      for (int ni = 0; ni < 4; ++ni)
        b[ni] = *(const bf16x8*)(bp + (long)(fq * 4 + ni) * 640 * 512);
      #pragma unroll
      for (int ae = 0; ae < 4; ++ae)
        #pragma unroll
        for (int bf = 0; bf < 4; ++bf)
          acc[ae][bf] = mfma16(a[ae], b[bf], acc[ae][bf]);
    }
  }
  bf16_t* pp = part + (long)blockIdx.y * (256 * 4096);
  #pragma unroll
  for (int ae = 0; ae < 4; ++ae) {
    int eblk16 = (e0 >> 4) + eh * 4 + ae;
    #pragma unroll
    for (int bf = 0; bf < 4; ++bf) {
      int fblk = fq * 4 + bf;
      f32x4 v = acc[ae][bf];
      bf16x4 pk;
      for (int r = 0; r < 4; ++r) pk[r] = (__bf16)v[r];
      *(bf16x4*)(pp + (((long)eblk16 * 16 + fblk) * 64 + l) * 4) = pk;
    }
  }
}

// Hef[f][e] (fragment-major) = es[e] * sum_s part[s][...]
__global__ __launch_bounds__(256) void reduce_he(const bf16_t* __restrict__ part,
                                                 const float* __restrict__ es,
                                                 bf16_t* __restrict__ Hef) {
  int u = blockIdx.x * 256 + threadIdx.x;      // 0..262143
  int lane = u & 63, tile = u >> 6;
  int fblk = tile & 15, eblk16 = tile >> 4;
  int lr = lane & 15, lq = lane >> 4;
  int e_base = eblk16 * 16 + lq * 4;
  float a0 = 0.f, a1 = 0.f, a2 = 0.f, a3 = 0.f;
  #pragma unroll
  for (int s = 0; s < AT_S; ++s) {
    bf16x4 v = *(const bf16x4*)(part + (long)s * (256 * 4096) + (long)u * 4);
    a0 += (float)v[0]; a1 += (float)v[1]; a2 += (float)v[2]; a3 += (float)v[3];
  }
  f32x4 e4 = *(const f32x4*)(es + e_base);
  bf16x4 pk;
  pk[0] = (__bf16)(a0 * e4[0]); pk[1] = (__bf16)(a1 * e4[1]);
  pk[2] = (__bf16)(a2 * e4[2]); pk[3] = (__bf16)(a3 * e4[3]);
  int eblk32 = eblk16 >> 1;
  int lanep = ((eblk16 & 1) * 2 + (lq >> 1)) * 16 + lr;
  long slot = (((long)fblk * 128 + eblk32) * 64 + lanep) * 8 + (lq & 1) * 4;
  *(bf16x4*)(Hef + slot) = pk;
}

// -------- conv out: h[n][f] = relu(isd[n]*(Hb[n]@He) + bias) --------------
// FLOG=1: fuse logits = h @ out_w + out_b, skip writing h.
template<int FLOG>
__global__ __launch_bounds__(512) void out_gemm_kern(const bf16_t* __restrict__ Hef,
                                                     const bf16_t* __restrict__ Hb,
                                                     const float* __restrict__ isd,
                                                     const float* __restrict__ bias,
                                                     bf16_t* __restrict__ h,
                                                     const float* __restrict__ ow,
                                                     const float* __restrict__ ob,
                                                     float* __restrict__ out) {
  __shared__ float lgp[8][80][2];
  int t = threadIdx.x, l = t & 63, wv = t >> 6;
  int lr = l & 15, lq = l >> 4;
  long r0 = (long)blockIdx.x * 80;
  int fo = wv * 32;
  f32x4 acc[5][2] = {};
  const bf16_t* ap = Hb + (r0 + lr) * (long)NE + lq * 8;
  const bf16_t* bp = Hef + (long)(wv * 2) * 65536 + l * 8;
  bf16x8 a[5], b[2];
  #pragma unroll
  for (int mi = 0; mi < 5; ++mi) a[mi] = *(const bf16x8*)(ap + (long)mi * 16 * NE);
  b[0] = *(const bf16x8*)(bp);
  b[1] = *(const bf16x8*)(bp + 65536);
  for (int k0 = 32; k0 < NE; k0 += 32) {
    int eblk = k0 >> 5;
    bf16x8 an[5], bn[2];
    #pragma unroll
    for (int mi = 0; mi < 5; ++mi) an[mi] = *(const bf16x8*)(ap + (long)mi * 16 * NE + k0);
    bn[0] = *(const bf16x8*)(bp + eblk * 512);
    bn[1] = *(const bf16x8*)(bp + 65536 + eblk * 512);
    #pragma unroll
    for (int mi = 0; mi < 5; ++mi) {
      acc[mi][0] = mfma16(a[mi], b[0], acc[mi][0]);
      acc[mi][1] = mfma16(a[mi], b[1], acc[mi][1]);
    }
    #pragma unroll
    for (int mi = 0; mi < 5; ++mi) a[mi] = an[mi];
    b[0] = bn[0]; b[1] = bn[1];
  }
  #pragma unroll
  for (int mi = 0; mi < 5; ++mi) {
    acc[mi][0] = mfma16(a[mi], b[0], acc[mi][0]);
    acc[mi][1] = mfma16(a[mi], b[1], acc[mi][1]);
  }
  #pragma unroll
  for (int mi = 0; mi < 5; ++mi) {
    long nb = r0 + mi * 16 + lq * 4;
    #pragma unroll
    for (int r = 0; r < 4; ++r) {
      long n = nb + r;
      float sd = (n < NN) ? isd[n] : 0.f;
      float a0 = 0.f, a1 = 0.f;
      #pragma unroll
      for (int ni = 0; ni < 2; ++ni) {
        int f = fo + ni * 16 + lr;
        float vv = acc[mi][ni][r] * sd + bias[f];
        vv = vv > 0.f ? vv : 0.f;
        if constexpr (!FLOG) {
          if (n < NN) h[n * 256 + f] = (__bf16)vv;
        } else {
          a0 += vv * ow[f * 2];
          a1 += vv * ow[f * 2 + 1];
        }
      }
      if constexpr (FLOG) {
        #pragma unroll
        for (int m = 1; m < 16; m <<= 1) { a0 += __shfl_xor(a0, m); a1 += __shfl_xor(a1, m); }
        if (lr == 0) {
          int rowl = mi * 16 + lq * 4 + r;
          lgp[wv][rowl][0] = a0;
          lgp[wv][rowl][1] = a1;
        }
      }
    }
  }
  if constexpr (FLOG) {
    __syncthreads();
    if (t < 80) {
      float s0 = 0.f, s1 = 0.f;
      #pragma unroll
      for (int wvi = 0; wvi < 8; ++wvi) { s0 += lgp[wvi][t][0]; s1 += lgp[wvi][t][1]; }
      long n = r0 + t;
      if (n < NN) {
        out[n * 2]     = s0 + ob[0];
        out[n * 2 + 1] = s1 + ob[1];
      }
    }
  }
}

// ============================================================== launcher
extern "C" void kernel_launch(void* const* d_in, const int* in_sizes, int n_in,
                              void* d_out, int out_size, void* d_ws, size_t ws_size,
                              hipStream_t stream) {
  const float* x    = (const float*)d_in[0];
  const float* z    = (const float*)d_in[1];
  const float* H    = (const float*)d_in[2];
  const float* w    = (const float*)d_in[3];
  const float* psi_w = (const float*)d_in[4];
  const float* psi_b = (const float*)d_in[5];
  const float* phi_w = (const float*)d_in[6];
  const float* phi_b = (const float*)d_in[7];
  const float* g1_w  = (const float*)d_in[8];
  const float* g1_b  = (const float*)d_in[9];
  const float* g2_w  = (const float*)d_in[10];
  const float* g2_b  = (const float*)d_in[11];
  const float* th1   = (const float*)d_in[12];
  const float* b1    = (const float*)d_in[13];
  const float* th2   = (const float*)d_in[14];
  const float* b2    = (const float*)d_in[15];
  const float* out_w = (const float*)d_in[16];
  const float* out_b = (const float*)d_in[17];

  float* logits_out = (float*)d_out;                 // [20000][2]
  float* gate_out   = logits_out + (size_t)NN * 2;   // [20000][128]

  char* p = (char*)d_ws;
  auto alloc = [&](size_t bytes) { char* r = p; p += (bytes + 255) & ~(size_t)255; return r; };
  float* Dvp  = (float*)alloc((size_t)NEB * NNP * 4);   // 1.31 MB
  float* Dep  = (float*)alloc((size_t)NNB * NE * 4);    // 2.62 MB
  float* isd  = (float*)alloc((size_t)NN * 4);
  float* es   = (float*)alloc((size_t)NE * 4);
  bf16_t* cat   = (bf16_t*)alloc((size_t)NN * 256 * 2);
  bf16_t* hid1  = (bf16_t*)alloc((size_t)NN * 256 * 2);
  bf16_t* fusedb= (bf16_t*)alloc((size_t)NN * 128 * 2);
  bf16_t* Yf    = (bf16_t*)alloc((size_t)16 * 640 * 512 * 2);   // 10.49 MB
  bf16_t* Hef   = (bf16_t*)alloc((size_t)16 * 128 * 512 * 2);   // 2.1 MB
  bf16_t* h     = (bf16_t*)alloc((size_t)NN * 256 * 2);
  bf16_t* pbuf  = (bf16_t*)alloc((size_t)AT_S * 256 * 4096 * 2); // 33.5 MB
  bf16_t* Hb    = (bf16_t*)alloc((size_t)NNP * NE * 2);
  bf16_t* psi_wt = (bf16_t*)alloc(65536 * 2);
  bf16_t* phi_wt = (bf16_t*)alloc(32768 * 2);
  bf16_t* g1_wt  = (bf16_t*)alloc(65536 * 2);
  bf16_t* g2_wt  = (bf16_t*)alloc(32768 * 2);
  bf16_t* th1_wt = (bf16_t*)alloc(32768 * 2);
  bf16_t* th2_wt = (bf16_t*)alloc(65536 * 2);

  cvtw_kern<<<1152, 256, 0, stream>>>(psi_w, phi_w, g1_w, g2_w, th1, th2,
                                      psi_wt, phi_wt, g1_wt, g2_wt, th1_wt, th2_wt);
  stats_cvt_kern<<<dim3(NEB, NNB), 256, 0, stream>>>(H, w, Dvp, Dep, Hb);
  finalize_kern<<<79, 256, 0, stream>>>(Dvp, Dep, w, isd, es);

  // front-end MLP chain
  gemm_node_kern<true,  EPI_CAT ><<<dim3(625, 1), 256, 0, stream>>>(x, 512, psi_wt, 512, psi_b, nullptr, cat,       256, nullptr, nullptr);
  gemm_node_kern<true,  EPI_CAT ><<<dim3(625, 1), 256, 0, stream>>>(z, 256, phi_wt, 256, phi_b, nullptr, cat + 128, 256, nullptr, nullptr);
  gemm_node_kern<false, EPI_RELU><<<dim3(625, 2), 256, 0, stream>>>(cat, 256, g1_wt, 256, g1_b, nullptr, hid1, 256, nullptr, nullptr);
  gemm_node_kern<false, EPI_GATE><<<dim3(625, 1), 256, 0, stream>>>(hid1, 256, g2_wt, 256, g2_b, gate_out, fusedb, 128, cat, nullptr);

  // hconv 1
  gemm_node_kern<false, EPI_Y><<<dim3(640, 2), 256, 0, stream>>>(fusedb, 128, th1_wt, 128, nullptr, nullptr, Yf, 0, nullptr, isd);
  at_gemm_kern<<<dim3(32, AT_S), 512, 0, stream>>>(Hb, Yf, pbuf);
  reduce_he<<<1024, 256, 0, stream>>>(pbuf, es, Hef);
  out_gemm_kern<0><<<256, 512, 0, stream>>>(Hef, Hb, isd, b1, h, nullptr, nullptr, nullptr);

  // hconv 2 (logits fused into out_gemm epilogue)
  gemm_node_kern<false, EPI_Y><<<dim3(640, 2), 256, 0, stream>>>(h, 256, th2_wt, 256, nullptr, nullptr, Yf, 0, nullptr, isd);
  at_gemm_kern<<<dim3(32, AT_S), 512, 0, stream>>>(Hb, Yf, pbuf);
  reduce_he<<<1024, 256, 0, stream>>>(pbuf, es, Hef);
  out_gemm_kern<1><<<256, 512, 0, stream>>>(Hef, Hb, isd, b2, nullptr, out_w, out_b, logits_out);

  (void)in_sizes; (void)n_in; (void)out_size; (void)ws_size;
}

// Round 8
// 597.530 us; speedup vs baseline: 2.2487x; 1.2381x over previous
//
#include <hip/hip_runtime.h>
#include <hip/hip_bf16.h>

// DF-HGNN fused pipeline v8: Hb stored column-panel-tiled Hbp[e/64][n][64] so
// all GEMM panel streams are dense; out_gemm rebuilt with LDS-staged A
// (fragment-ordered, double-buffered, 64 rows x 320 blocks).
// N=20000, E=4096, IN=512, DET=256, HID=256, HALF=128, OUT=2.

typedef __bf16 bf16_t;
typedef __attribute__((ext_vector_type(8))) __bf16 bf16x8;
typedef __attribute__((ext_vector_type(4))) __bf16 bf16x4;
typedef __attribute__((ext_vector_type(4))) float f32x4;

#define NN 20000
#define NE 4096
#define NNP 20480           // 640*32 padded node extent (zero rows >= NN)
#define AT_S 16             // n-split for H^T @ Y (32 e-blocks x 16 = 512)
#define NEB 16              // e-blocks in stats grid (256 cols each)
#define NNB 160             // n-blocks in stats grid (128 rows each)
// Layouts:
//  Hbp [p=e>>6][n][e&63]               : column-panel-tiled bf16 H
//  Yf  [fblk 16][nblk 640][lane 64][8] : value(f,n) at lane=((n&31)>>3)*16+(f&15), j=n&7
//  Hef [fblk 16][eblk 128][lane 64][8] : value(f,e) same scheme with k=e
//  part[s][tile=eblk16*16+fblk][lane 64][4]

__device__ __forceinline__ f32x4 mfma16(bf16x8 a, bf16x8 b, f32x4 c) {
  return __builtin_amdgcn_mfma_f32_16x16x32_bf16(a, b, c, 0, 0, 0);
}

// ---------------- fused stats + bf16 cast: Dvp, Dep, Hbp -------------------
// grid (16 e-blocks x 256 cols, 160 n-blocks x 128 rows). Lane l owns cols
// e0+4l..4l+3: 1KB-dense loads; Hbp writes = 4x128B segments per wave.
__global__ __launch_bounds__(256) void stats_cvt_kern(const float* __restrict__ H,
                                                      const float* __restrict__ w,
                                                      float* __restrict__ Dvp,
                                                      float* __restrict__ Dep,
                                                      bf16_t* __restrict__ Hbp) {
  __shared__ float dvl[128];
  __shared__ float deP[4][256];
  int t = threadIdx.x, l = t & 63, wv = t >> 6;
  long e0 = (long)blockIdx.x * 256;
  long n0 = (long)blockIdx.y * 128;
  long pbase = ((e0 >> 6) + (l >> 4)) * (long)NNP;
  int inner = (l & 15) * 4;
  f32x4 w4 = *(const f32x4*)(w + e0 + l * 4);
  f32x4 de; de[0] = de[1] = de[2] = de[3] = 0.f;
  #pragma unroll 4
  for (int i = 0; i < 32; ++i) {
    long row = n0 + wv * 32 + i;
    float s;
    if (row < NN) {
      f32x4 u = *(const f32x4*)(H + row * NE + e0 + l * 4);
      bf16x4 pk;
      #pragma unroll
      for (int j = 0; j < 4; ++j) pk[j] = (__bf16)u[j];
      *(bf16x4*)(Hbp + (pbase + row) * 64 + inner) = pk;
      de += u;
      s = u[0] * w4[0] + u[1] * w4[1] + u[2] * w4[2] + u[3] * w4[3];
    } else {
      bf16x4 z;
      #pragma unroll
      for (int j = 0; j < 4; ++j) z[j] = (__bf16)0.f;
      *(bf16x4*)(Hbp + (pbase + row) * 64 + inner) = z;
      s = 0.f;
    }
    #pragma unroll
    for (int m = 1; m < 64; m <<= 1) s += __shfl_xor(s, m);
    if (l == 0) dvl[wv * 32 + i] = s;
  }
  *(f32x4*)(&deP[wv][l * 4]) = de;
  __syncthreads();
  if (t < 128) Dvp[(long)blockIdx.x * NNP + n0 + t] = dvl[t];
  {
    float s = deP[0][t] + deP[1][t] + deP[2][t] + deP[3][t];
    Dep[(long)blockIdx.y * NE + e0 + t] = s;
  }
}

// isd[n] = rsqrt(max(sum_b Dvp, eps));  es[e] = w/max(sum_b Dep, eps)
__global__ __launch_bounds__(256) void finalize_kern(const float* __restrict__ Dvp,
                                                     const float* __restrict__ Dep,
                                                     const float* __restrict__ w,
                                                     float* __restrict__ isd,
                                                     float* __restrict__ es) {
  int t = blockIdx.x * 256 + threadIdx.x;
  if (t < NN) {
    float s = 0.f;
    #pragma unroll 8
    for (int b = 0; b < NEB; ++b) s += Dvp[(long)b * NNP + t];
    isd[t] = rsqrtf(fmaxf(s, 1e-6f));
  }
  if (t < NE) {
    float s = 0.f;
    #pragma unroll 8
    for (int b = 0; b < NNB; ++b) s += Dep[(long)b * NE + t];
    es[t] = w[t] / fmaxf(s, 1e-6f);
  }
}

// -------------------------------------------- weight transpose+cast (tiny)
__global__ void cvtw_kern(const float* __restrict__ psi, const float* __restrict__ phi,
                          const float* __restrict__ g1,  const float* __restrict__ g2,
                          const float* __restrict__ th1, const float* __restrict__ th2,
                          bf16_t* dpsi, bf16_t* dphi, bf16_t* dg1, bf16_t* dg2,
                          bf16_t* dth1, bf16_t* dth2) {
  int t = blockIdx.x * 256 + threadIdx.x;
  if (t < 65536) {
    int nc = t >> 9, k = t & 511; dpsi[t] = (__bf16)psi[k * 128 + nc];
  } else if (t < 98304) {
    int i = t - 65536; int nc = i >> 8, k = i & 255; dphi[i] = (__bf16)phi[k * 128 + nc];
  } else if (t < 163840) {
    int i = t - 98304; int nc = i >> 8, k = i & 255; dg1[i] = (__bf16)g1[k * 256 + nc];
  } else if (t < 196608) {
    int i = t - 163840; int nc = i >> 8, k = i & 255; dg2[i] = (__bf16)g2[k * 128 + nc];
  } else if (t < 229376) {
    int i = t - 196608; int nc = i >> 7, k = i & 127; dth1[i] = (__bf16)th1[k * 256 + nc];
  } else if (t < 294912) {
    int i = t - 229376; int nc = i >> 8, k = i & 255; dth2[i] = (__bf16)th2[k * 256 + nc];
  }
}

// --------------------------------------------------- node-feature GEMMs
enum { EPI_CAT = 0, EPI_RELU = 1, EPI_GATE = 2, EPI_Y = 3 };

template<bool AF32, int EPI>
__global__ __launch_bounds__(256) void gemm_node_kern(
    const void* __restrict__ Av, int lda, const bf16_t* __restrict__ Bt, int K,
    const float* __restrict__ bias, float* __restrict__ gate_out,
    bf16_t* __restrict__ dst, int ldc, const bf16_t* __restrict__ cat,
    const float* __restrict__ isd) {
  int tid = threadIdx.x, l = tid & 63, wv = tid >> 6;
  int lr = l & 15, lq = l >> 4;
  int hm = wv >> 1;
  int mo = blockIdx.x * 32 + hm * 16;
  int no = blockIdx.y * 128 + (wv & 1) * 64;
  f32x4 acc[4] = {};
  for (int k0 = 0; k0 < K; k0 += 32) {
    int row = mo + lr;
    bf16x8 a;
    if (row < NN) {
      if constexpr (AF32) {
        const float* ap = (const float*)Av + (long)row * lda + k0 + lq * 8;
        f32x4 u0 = *(const f32x4*)ap, u1 = *(const f32x4*)(ap + 4);
        #pragma unroll
        for (int j = 0; j < 4; ++j) { a[j] = (__bf16)u0[j]; a[j + 4] = (__bf16)u1[j]; }
      } else {
        a = *(const bf16x8*)((const bf16_t*)Av + (long)row * lda + k0 + lq * 8);
      }
    } else {
      #pragma unroll
      for (int j = 0; j < 8; ++j) a[j] = (__bf16)0.f;
    }
    #pragma unroll
    for (int ni = 0; ni < 4; ++ni) {
      bf16x8 b = *(const bf16x8*)(Bt + (long)(no + ni * 16 + lr) * K + k0 + lq * 8);
      acc[ni] = mfma16(a, b, acc[ni]);
    }
  }
  #pragma unroll
  for (int ni = 0; ni < 4; ++ni) {
    int colf = no + ni * 16 + lr;
    int rb = mo + lq * 4;
    f32x4 v = acc[ni];
    if constexpr (EPI == EPI_CAT) {
      float bs = bias[colf];
      for (int r = 0; r < 4; ++r) { int n = rb + r;
        if (n < NN) dst[(long)n * ldc + colf] = (__bf16)(v[r] + bs); }
    } else if constexpr (EPI == EPI_RELU) {
      float bs = bias[colf];
      for (int r = 0; r < 4; ++r) { int n = rb + r;
        if (n < NN) { float xx = v[r] + bs; dst[(long)n * ldc + colf] = (__bf16)(xx > 0.f ? xx : 0.f); } }
    } else if constexpr (EPI == EPI_GATE) {
      float bs = bias[colf];
      for (int r = 0; r < 4; ++r) {
        int n = rb + r;
        if (n < NN) {
          float g = 1.f / (1.f + __expf(-(v[r] + bs)));
          gate_out[(long)n * 128 + colf] = g;
          float px = (float)cat[(long)n * 256 + colf];
          float pz = (float)cat[(long)n * 256 + 128 + colf];
          dst[(long)n * 128 + colf] = (__bf16)(g * pz + (1.f - g) * px);
        }
      }
    } else {  // EPI_Y: fragment-major Yf, coalesced 8B store per ni
      int fblk = (no >> 4) + ni;
      int nblk = blockIdx.x;
      int lanep = (hm * 2 + (lq >> 1)) * 16 + lr;
      bf16x4 pk;
      for (int r = 0; r < 4; ++r) {
        int nr = rb + r;
        float sc = (nr < NN) ? isd[nr] : 0.f;
        pk[r] = (__bf16)(v[r] * sc);
      }
      *(bf16x4*)(dst + (((long)fblk * 640 + nblk) * 64 + lanep) * 8 + (lq & 1) * 4) = pk;
    }
  }
}

// --------------------------------------------- He partials: fragment-major
// He[e][f] = sum_n Hbp panel rows * Y[f][n]. 8 waves, 128e x 256f tile,
// BK=64. Staging reads now 1KB-dense (panel-tiled Hbp).
__global__ __launch_bounds__(512) void at_gemm_kern(const bf16_t* __restrict__ Hbp,
                                                    const bf16_t* __restrict__ Yf,
                                                    bf16_t* __restrict__ part) {
  __shared__ bf16_t T[128 * 72];       // [e_local][64 n + pad]
  int t = threadIdx.x, l = t & 63, wv = t >> 6;
  int lr = l & 15, lq = l >> 4;
  int eh = wv >> 2, fq = wv & 3;       // wave: e-half, f-quarter
  int e0 = blockIdx.x * 128;
  int s0 = blockIdx.y * 20, s1 = s0 + 20;   // BK64 steps
  int rp = t >> 4;                     // row-pair 0..31 (64 rows)
  int ck = t & 15;                     // 8-e column chunk
  f32x4 acc[4][4] = {};
  // panel-tiled source: panel (e0>>6)+(ck>>3), row s0*64+2rp, inner (ck&7)*8
  const bf16_t* src = Hbp + (((long)(e0 >> 6) + (ck >> 3)) * NNP + (long)s0 * 64 + 2 * rp) * 64
                          + (ck & 7) * 8;
  bf16x8 ra = *(const bf16x8*)src;
  bf16x8 rb = *(const bf16x8*)(src + 64);
  for (int s = s0; s < s1; ++s) {
    __syncthreads();
    #pragma unroll
    for (int j = 0; j < 8; ++j) {
      int jj = (j + ck) & 7;           // rotation -> 32 banks, exact 2-way (free)
      int el = ck * 8 + jj;
      unsigned lo = (unsigned)__builtin_bit_cast(unsigned short, (__bf16)ra[jj]);
      unsigned hi = (unsigned)__builtin_bit_cast(unsigned short, (__bf16)rb[jj]);
      *(unsigned*)(T + el * 72 + rp * 2) = lo | (hi << 16);
    }
    __syncthreads();
    if (s + 1 < s1) {                  // prefetch next 64-row stripe (dense)
      src += 64 * 64;
      ra = *(const bf16x8*)src;
      rb = *(const bf16x8*)(src + 64);
    }
    #pragma unroll
    for (int k32 = 0; k32 < 2; ++k32) {
      bf16x8 a[4], b[4];
      #pragma unroll
      for (int ni = 0; ni < 4; ++ni)
        a[ni] = *(const bf16x8*)(T + (eh * 64 + ni * 16 + lr) * 72 + k32 * 32 + lq * 8);
      const bf16_t* bp = Yf + ((long)(s * 2 + k32) * 64 + l) * 8;
      #pragma unroll
      for (int ni = 0; ni < 4; ++ni)
        b[ni] = *(const bf16x8*)(bp + (long)(fq * 4 + ni) * 640 * 512);
      #pragma unroll
      for (int ae = 0; ae < 4; ++ae)
        #pragma unroll
        for (int bf = 0; bf < 4; ++bf)
          acc[ae][bf] = mfma16(a[ae], b[bf], acc[ae][bf]);
    }
  }
  bf16_t* pp = part + (long)blockIdx.y * (256 * 4096);
  #pragma unroll
  for (int ae = 0; ae < 4; ++ae) {
    int eblk16 = (e0 >> 4) + eh * 4 + ae;
    #pragma unroll
    for (int bf = 0; bf < 4; ++bf) {
      int fblk = fq * 4 + bf;
      f32x4 v = acc[ae][bf];
      bf16x4 pk;
      for (int r = 0; r < 4; ++r) pk[r] = (__bf16)v[r];
      *(bf16x4*)(pp + (((long)eblk16 * 16 + fblk) * 64 + l) * 4) = pk;
    }
  }
}

// Hef[f][e] (fragment-major) = es[e] * sum_s part[s][...]
__global__ __launch_bounds__(256) void reduce_he(const bf16_t* __restrict__ part,
                                                 const float* __restrict__ es,
                                                 bf16_t* __restrict__ Hef) {
  int u = blockIdx.x * 256 + threadIdx.x;      // 0..262143
  int lane = u & 63, tile = u >> 6;
  int fblk = tile & 15, eblk16 = tile >> 4;
  int lr = lane & 15, lq = lane >> 4;
  int e_base = eblk16 * 16 + lq * 4;
  float a0 = 0.f, a1 = 0.f, a2 = 0.f, a3 = 0.f;
  #pragma unroll
  for (int s = 0; s < AT_S; ++s) {
    bf16x4 v = *(const bf16x4*)(part + (long)s * (256 * 4096) + (long)u * 4);
    a0 += (float)v[0]; a1 += (float)v[1]; a2 += (float)v[2]; a3 += (float)v[3];
  }
  f32x4 e4 = *(const f32x4*)(es + e_base);
  bf16x4 pk;
  pk[0] = (__bf16)(a0 * e4[0]); pk[1] = (__bf16)(a1 * e4[1]);
  pk[2] = (__bf16)(a2 * e4[2]); pk[3] = (__bf16)(a3 * e4[3]);
  int eblk32 = eblk16 >> 1;
  int lanep = ((eblk16 & 1) * 2 + (lq >> 1)) * 16 + lr;
  long slot = (((long)fblk * 128 + eblk32) * 64 + lanep) * 8 + (lq & 1) * 4;
  *(bf16x4*)(Hef + slot) = pk;
}

// -------- conv out: h[n][f] = relu(isd[n]*(Hbp[n]@He) + bias) -------------
// 320 blocks x 64 rows, 8 waves, BK=64. A staged via LDS in fragment order
// (lane-linear, conflict-free b128), double-buffered, 1 barrier/step.
// Wave w loads frag w (mi=w>>1, k32=w&1); dense 8KB tile per (block,step).
// FLOG=1: fuse logits, skip writing h.
template<int FLOG>
__global__ __launch_bounds__(512) void out_gemm_kern(const bf16_t* __restrict__ Hef,
                                                     const bf16_t* __restrict__ Hbp,
                                                     const float* __restrict__ isd,
                                                     const float* __restrict__ bias,
                                                     bf16_t* __restrict__ h,
                                                     const float* __restrict__ ow,
                                                     const float* __restrict__ ob,
                                                     float* __restrict__ out) {
  __shared__ bf16_t lbuf[2][4096];     // [buf][frag 8][lane 64][8]
  __shared__ float lgp[8][64][2];
  int t = threadIdx.x, l = t & 63, wv = t >> 6;
  int lr = l & 15, lq = l >> 4;
  long r0 = (long)blockIdx.x * 64;
  f32x4 acc[4][2] = {};
  // this wave's staging source: frag wv -> rows r0+(wv>>1)*16+lr, inner (wv&1)*32+lq*8
  const bf16_t* asrc = Hbp + (r0 + (wv >> 1) * 16 + lr) * 64 + (wv & 1) * 32 + lq * 8;
  const bf16_t* bbase = Hef + (long)l * 8;
  bf16x8 rg = *(const bf16x8*)asrc;
  int c = 0;
  for (int s = 0; s < 64; ++s) {
    *(bf16x8*)(&lbuf[c][wv * 512 + l * 8]) = rg;
    __syncthreads();
    if (s + 1 < 64) rg = *(const bf16x8*)(asrc + (long)(s + 1) * NNP * 64);
    #pragma unroll
    for (int k32 = 0; k32 < 2; ++k32) {
      bf16x8 a[4], b[2];
      #pragma unroll
      for (int mi = 0; mi < 4; ++mi)
        a[mi] = *(const bf16x8*)(&lbuf[c][(mi * 2 + k32) * 512 + l * 8]);
      int eblk = s * 2 + k32;
      #pragma unroll
      for (int ni = 0; ni < 2; ++ni)
        b[ni] = *(const bf16x8*)(bbase + ((long)(wv * 2 + ni) * 128 + eblk) * 512);
      #pragma unroll
      for (int mi = 0; mi < 4; ++mi) {
        acc[mi][0] = mfma16(a[mi], b[0], acc[mi][0]);
        acc[mi][1] = mfma16(a[mi], b[1], acc[mi][1]);
      }
    }
    c ^= 1;
  }
  #pragma unroll
  for (int mi = 0; mi < 4; ++mi) {
    long nb = r0 + mi * 16 + lq * 4;
    #pragma unroll
    for (int r = 0; r < 4; ++r) {
      long n = nb + r;
      float sd = (n < NN) ? isd[n] : 0.f;
      float a0 = 0.f, a1 = 0.f;
      #pragma unroll
      for (int ni = 0; ni < 2; ++ni) {
        int f = wv * 32 + ni * 16 + lr;
        float vv = acc[mi][ni][r] * sd + bias[f];
        vv = vv > 0.f ? vv : 0.f;
        if constexpr (!FLOG) {
          if (n < NN) h[n * 256 + f] = (__bf16)vv;
        } else {
          a0 += vv * ow[f * 2];
          a1 += vv * ow[f * 2 + 1];
        }
      }
      if constexpr (FLOG) {
        #pragma unroll
        for (int m = 1; m < 16; m <<= 1) { a0 += __shfl_xor(a0, m); a1 += __shfl_xor(a1, m); }
        if (lr == 0) {
          int rowl = mi * 16 + lq * 4 + r;
          lgp[wv][rowl][0] = a0;
          lgp[wv][rowl][1] = a1;
        }
      }
    }
  }
  if constexpr (FLOG) {
    __syncthreads();
    if (t < 64) {
      float s0 = 0.f, s1 = 0.f;
      #pragma unroll
      for (int wvi = 0; wvi < 8; ++wvi) { s0 += lgp[wvi][t][0]; s1 += lgp[wvi][t][1]; }
      long n = r0 + t;
      if (n < NN) {
        out[n * 2]     = s0 + ob[0];
        out[n * 2 + 1] = s1 + ob[1];
      }
    }
  }
}

// ============================================================== launcher
extern "C" void kernel_launch(void* const* d_in, const int* in_sizes, int n_in,
                              void* d_out, int out_size, void* d_ws, size_t ws_size,
                              hipStream_t stream) {
  const float* x    = (const float*)d_in[0];
  const float* z    = (const float*)d_in[1];
  const float* H    = (const float*)d_in[2];
  const float* w    = (const float*)d_in[3];
  const float* psi_w = (const float*)d_in[4];
  const float* psi_b = (const float*)d_in[5];
  const float* phi_w = (const float*)d_in[6];
  const float* phi_b = (const float*)d_in[7];
  const float* g1_w  = (const float*)d_in[8];
  const float* g1_b  = (const float*)d_in[9];
  const float* g2_w  = (const float*)d_in[10];
  const float* g2_b  = (const float*)d_in[11];
  const float* th1   = (const float*)d_in[12];
  const float* b1    = (const float*)d_in[13];
  const float* th2   = (const float*)d_in[14];
  const float* b2    = (const float*)d_in[15];
  const float* out_w = (const float*)d_in[16];
  const float* out_b = (const float*)d_in[17];

  float* logits_out = (float*)d_out;                 // [20000][2]
  float* gate_out   = logits_out + (size_t)NN * 2;   // [20000][128]

  char* p = (char*)d_ws;
  auto alloc = [&](size_t bytes) { char* r = p; p += (bytes + 255) & ~(size_t)255; return r; };
  float* Dvp  = (float*)alloc((size_t)NEB * NNP * 4);   // 1.31 MB
  float* Dep  = (float*)alloc((size_t)NNB * NE * 4);    // 2.62 MB
  float* isd  = (float*)alloc((size_t)NN * 4);
  float* es   = (float*)alloc((size_t)NE * 4);
  bf16_t* cat   = (bf16_t*)alloc((size_t)NN * 256 * 2);
  bf16_t* hid1  = (bf16_t*)alloc((size_t)NN * 256 * 2);
  bf16_t* fusedb= (bf16_t*)alloc((size_t)NN * 128 * 2);
  bf16_t* Yf    = (bf16_t*)alloc((size_t)16 * 640 * 512 * 2);   // 10.49 MB
  bf16_t* Hef   = (bf16_t*)alloc((size_t)16 * 128 * 512 * 2);   // 2.1 MB
  bf16_t* h     = (bf16_t*)alloc((size_t)NN * 256 * 2);
  bf16_t* pbuf  = (bf16_t*)alloc((size_t)AT_S * 256 * 4096 * 2); // 33.5 MB
  bf16_t* Hbp   = (bf16_t*)alloc((size_t)NNP * NE * 2);          // 168 MB
  bf16_t* psi_wt = (bf16_t*)alloc(65536 * 2);
  bf16_t* phi_wt = (bf16_t*)alloc(32768 * 2);
  bf16_t* g1_wt  = (bf16_t*)alloc(65536 * 2);
  bf16_t* g2_wt  = (bf16_t*)alloc(32768 * 2);
  bf16_t* th1_wt = (bf16_t*)alloc(32768 * 2);
  bf16_t* th2_wt = (bf16_t*)alloc(65536 * 2);

  cvtw_kern<<<1152, 256, 0, stream>>>(psi_w, phi_w, g1_w, g2_w, th1, th2,
                                      psi_wt, phi_wt, g1_wt, g2_wt, th1_wt, th2_wt);
  stats_cvt_kern<<<dim3(NEB, NNB), 256, 0, stream>>>(H, w, Dvp, Dep, Hbp);
  finalize_kern<<<79, 256, 0, stream>>>(Dvp, Dep, w, isd, es);

  // front-end MLP chain
  gemm_node_kern<true,  EPI_CAT ><<<dim3(625, 1), 256, 0, stream>>>(x, 512, psi_wt, 512, psi_b, nullptr, cat,       256, nullptr, nullptr);
  gemm_node_kern<true,  EPI_CAT ><<<dim3(625, 1), 256, 0, stream>>>(z, 256, phi_wt, 256, phi_b, nullptr, cat + 128, 256, nullptr, nullptr);
  gemm_node_kern<false, EPI_RELU><<<dim3(625, 2), 256, 0, stream>>>(cat, 256, g1_wt, 256, g1_b, nullptr, hid1, 256, nullptr, nullptr);
  gemm_node_kern<false, EPI_GATE><<<dim3(625, 1), 256, 0, stream>>>(hid1, 256, g2_wt, 256, g2_b, gate_out, fusedb, 128, cat, nullptr);

  // hconv 1
  gemm_node_kern<false, EPI_Y><<<dim3(640, 2), 256, 0, stream>>>(fusedb, 128, th1_wt, 128, nullptr, nullptr, Yf, 0, nullptr, isd);
  at_gemm_kern<<<dim3(32, AT_S), 512, 0, stream>>>(Hbp, Yf, pbuf);
  reduce_he<<<1024, 256, 0, stream>>>(pbuf, es, Hef);
  out_gemm_kern<0><<<320, 512, 0, stream>>>(Hef, Hbp, isd, b1, h, nullptr, nullptr, nullptr);

  // hconv 2 (logits fused into out_gemm epilogue)
  gemm_node_kern<false, EPI_Y><<<dim3(640, 2), 256, 0, stream>>>(h, 256, th2_wt, 256, nullptr, nullptr, Yf, 0, nullptr, isd);
  at_gemm_kern<<<dim3(32, AT_S), 512, 0, stream>>>(Hbp, Yf, pbuf);
  reduce_he<<<1024, 256, 0, stream>>>(pbuf, es, Hef);
  out_gemm_kern<1><<<320, 512, 0, stream>>>(Hef, Hbp, isd, b2, nullptr, out_w, out_b, logits_out);

  (void)in_sizes; (void)n_in; (void)out_size; (void)ws_size;
}

// Round 9
// 580.050 us; speedup vs baseline: 2.3165x; 1.0301x over previous
//
#include <hip/hip_runtime.h>
#include <hip/hip_bf16.h>

// DF-HGNN fused pipeline v9: producer->consumer fusions.
//  - gate_y_kern: g2-gate + fused + Y1=fused@th1*isd in one block (K complete).
//  - out_gemm<1>: conv1 output tile + Y2=h@th2*isd fused (h never hits HBM).
// N=20000, E=4096, IN=512, DET=256, HID=256, HALF=128, OUT=2.

typedef __bf16 bf16_t;
typedef __attribute__((ext_vector_type(8))) __bf16 bf16x8;
typedef __attribute__((ext_vector_type(4))) __bf16 bf16x4;
typedef __attribute__((ext_vector_type(4))) float f32x4;

#define NN 20000
#define NE 4096
#define NNP 20480           // 640*32 padded node extent
#define AT_S 16             // n-split for H^T @ Y
#define NEB 16              // e-blocks in stats grid (256 cols each)
#define NNB 160             // n-blocks in stats grid (128 rows each)
// Layouts:
//  Hbp [p=e>>6][n][e&63]               : column-panel-tiled bf16 H
//  Yf  [fblk 16][nblk 640][lane 64][8] : value(f,n) at lane=((n&31)>>3)*16+(f&15), j=n&7
//  Hef [fblk 16][eblk 128][lane 64][8] : value(f,e) same scheme with k=e
//  part[s][tile=eblk16*16+fblk][lane 64][4]

__device__ __forceinline__ f32x4 mfma16(bf16x8 a, bf16x8 b, f32x4 c) {
  return __builtin_amdgcn_mfma_f32_16x16x32_bf16(a, b, c, 0, 0, 0);
}

// ---------------- fused stats + bf16 cast: Dvp, Dep, Hbp -------------------
__global__ __launch_bounds__(256) void stats_cvt_kern(const float* __restrict__ H,
                                                      const float* __restrict__ w,
                                                      float* __restrict__ Dvp,
                                                      float* __restrict__ Dep,
                                                      bf16_t* __restrict__ Hbp) {
  __shared__ float dvl[128];
  __shared__ float deP[4][256];
  int t = threadIdx.x, l = t & 63, wv = t >> 6;
  long e0 = (long)blockIdx.x * 256;
  long n0 = (long)blockIdx.y * 128;
  long pbase = ((e0 >> 6) + (l >> 4)) * (long)NNP;
  int inner = (l & 15) * 4;
  f32x4 w4 = *(const f32x4*)(w + e0 + l * 4);
  f32x4 de; de[0] = de[1] = de[2] = de[3] = 0.f;
  #pragma unroll 4
  for (int i = 0; i < 32; ++i) {
    long row = n0 + wv * 32 + i;
    float s;
    if (row < NN) {
      f32x4 u = *(const f32x4*)(H + row * NE + e0 + l * 4);
      bf16x4 pk;
      #pragma unroll
      for (int j = 0; j < 4; ++j) pk[j] = (__bf16)u[j];
      *(bf16x4*)(Hbp + (pbase + row) * 64 + inner) = pk;
      de += u;
      s = u[0] * w4[0] + u[1] * w4[1] + u[2] * w4[2] + u[3] * w4[3];
    } else {
      bf16x4 z;
      #pragma unroll
      for (int j = 0; j < 4; ++j) z[j] = (__bf16)0.f;
      *(bf16x4*)(Hbp + (pbase + row) * 64 + inner) = z;
      s = 0.f;
    }
    #pragma unroll
    for (int m = 1; m < 64; m <<= 1) s += __shfl_xor(s, m);
    if (l == 0) dvl[wv * 32 + i] = s;
  }
  *(f32x4*)(&deP[wv][l * 4]) = de;
  __syncthreads();
  if (t < 128) Dvp[(long)blockIdx.x * NNP + n0 + t] = dvl[t];
  {
    float s = deP[0][t] + deP[1][t] + deP[2][t] + deP[3][t];
    Dep[(long)blockIdx.y * NE + e0 + t] = s;
  }
}

__global__ __launch_bounds__(256) void finalize_kern(const float* __restrict__ Dvp,
                                                     const float* __restrict__ Dep,
                                                     const float* __restrict__ w,
                                                     float* __restrict__ isd,
                                                     float* __restrict__ es) {
  int t = blockIdx.x * 256 + threadIdx.x;
  if (t < NN) {
    float s = 0.f;
    #pragma unroll 8
    for (int b = 0; b < NEB; ++b) s += Dvp[(long)b * NNP + t];
    isd[t] = rsqrtf(fmaxf(s, 1e-6f));
  }
  if (t < NE) {
    float s = 0.f;
    #pragma unroll 8
    for (int b = 0; b < NNB; ++b) s += Dep[(long)b * NE + t];
    es[t] = w[t] / fmaxf(s, 1e-6f);
  }
}

// -------------------------------------------- weight transpose+cast (tiny)
__global__ void cvtw_kern(const float* __restrict__ psi, const float* __restrict__ phi,
                          const float* __restrict__ g1,  const float* __restrict__ g2,
                          const float* __restrict__ th1, const float* __restrict__ th2,
                          bf16_t* dpsi, bf16_t* dphi, bf16_t* dg1, bf16_t* dg2,
                          bf16_t* dth1, bf16_t* dth2) {
  int t = blockIdx.x * 256 + threadIdx.x;
  if (t < 65536) {
    int nc = t >> 9, k = t & 511; dpsi[t] = (__bf16)psi[k * 128 + nc];
  } else if (t < 98304) {
    int i = t - 65536; int nc = i >> 8, k = i & 255; dphi[i] = (__bf16)phi[k * 128 + nc];
  } else if (t < 163840) {
    int i = t - 98304; int nc = i >> 8, k = i & 255; dg1[i] = (__bf16)g1[k * 256 + nc];
  } else if (t < 196608) {
    int i = t - 163840; int nc = i >> 8, k = i & 255; dg2[i] = (__bf16)g2[k * 128 + nc];
  } else if (t < 229376) {
    int i = t - 196608; int nc = i >> 7, k = i & 127; dth1[i] = (__bf16)th1[k * 256 + nc];
  } else if (t < 294912) {
    int i = t - 229376; int nc = i >> 8, k = i & 255; dth2[i] = (__bf16)th2[k * 256 + nc];
  }
}

// --------------------------------------------------- node-feature GEMMs
enum { EPI_CAT = 0, EPI_RELU = 1 };

template<bool AF32, int EPI>
__global__ __launch_bounds__(256) void gemm_node_kern(
    const void* __restrict__ Av, int lda, const bf16_t* __restrict__ Bt, int K,
    const float* __restrict__ bias, bf16_t* __restrict__ dst, int ldc) {
  int tid = threadIdx.x, l = tid & 63, wv = tid >> 6;
  int lr = l & 15, lq = l >> 4;
  int hm = wv >> 1;
  int mo = blockIdx.x * 32 + hm * 16;
  int no = blockIdx.y * 128 + (wv & 1) * 64;
  f32x4 acc[4] = {};
  for (int k0 = 0; k0 < K; k0 += 32) {
    int row = mo + lr;
    bf16x8 a;
    if (row < NN) {
      if constexpr (AF32) {
        const float* ap = (const float*)Av + (long)row * lda + k0 + lq * 8;
        f32x4 u0 = *(const f32x4*)ap, u1 = *(const f32x4*)(ap + 4);
        #pragma unroll
        for (int j = 0; j < 4; ++j) { a[j] = (__bf16)u0[j]; a[j + 4] = (__bf16)u1[j]; }
      } else {
        a = *(const bf16x8*)((const bf16_t*)Av + (long)row * lda + k0 + lq * 8);
      }
    } else {
      #pragma unroll
      for (int j = 0; j < 8; ++j) a[j] = (__bf16)0.f;
    }
    #pragma unroll
    for (int ni = 0; ni < 4; ++ni) {
      bf16x8 b = *(const bf16x8*)(Bt + (long)(no + ni * 16 + lr) * K + k0 + lq * 8);
      acc[ni] = mfma16(a, b, acc[ni]);
    }
  }
  #pragma unroll
  for (int ni = 0; ni < 4; ++ni) {
    int colf = no + ni * 16 + lr;
    int rb = mo + lq * 4;
    f32x4 v = acc[ni];
    float bs = bias[colf];
    for (int r = 0; r < 4; ++r) {
      int n = rb + r;
      if (n < NN) {
        float xx = v[r] + bs;
        if constexpr (EPI == EPI_RELU) xx = xx > 0.f ? xx : 0.f;
        dst[(long)n * ldc + colf] = (__bf16)xx;
      }
    }
  }
}

// ------------- fused gate + fused-features + Y1 = fused@th1*isd -----------
// grid 640 x 256thr (4 waves). Blocks >=625 write Yf pad zeros.
// Phase1: gate[32][128] = sigmoid(hid1@g2+b) (K=256); fused -> LDS [32][132].
// Phase2: Y1[32][256] = fused@th1 (K=128), EPI_Y fragment store * isd.
__global__ __launch_bounds__(256) void gate_y_kern(
    const bf16_t* __restrict__ hid1, const bf16_t* __restrict__ g2w,
    const float* __restrict__ g2b, const bf16_t* __restrict__ cat,
    const bf16_t* __restrict__ th1w, const float* __restrict__ isd,
    float* __restrict__ gate_out, bf16_t* __restrict__ Yf) {
  __shared__ bf16_t fl[32 * 132];     // fused tile, stride 132 bf16
  int t = threadIdx.x, l = t & 63, wv = t >> 6;
  int lr = l & 15, lq = l >> 4;
  if (blockIdx.x >= 625) {            // pad nblk: zero fragments
    bf16x8 z;
    #pragma unroll
    for (int j = 0; j < 8; ++j) z[j] = (__bf16)0.f;
    #pragma unroll
    for (int i = 0; i < 4; ++i)
      *(bf16x8*)(Yf + (((long)(wv + i * 4) * 640 + blockIdx.x) * 64 + l) * 8) = z;
    return;
  }
  long n0 = (long)blockIdx.x * 32;
  int hm = wv >> 1, nq = wv & 1;
  int mo = hm * 16, no = nq * 64;
  f32x4 acc[4] = {};
  for (int k0 = 0; k0 < 256; k0 += 32) {
    bf16x8 a = *(const bf16x8*)(hid1 + (n0 + mo + lr) * 256 + k0 + lq * 8);
    #pragma unroll
    for (int ni = 0; ni < 4; ++ni) {
      bf16x8 b = *(const bf16x8*)(g2w + (long)(no + ni * 16 + lr) * 256 + k0 + lq * 8);
      acc[ni] = mfma16(a, b, acc[ni]);
    }
  }
  #pragma unroll
  for (int ni = 0; ni < 4; ++ni) {
    int colf = no + ni * 16 + lr;
    float bs = g2b[colf];
    #pragma unroll
    for (int r = 0; r < 4; ++r) {
      long n = n0 + mo + lq * 4 + r;
      float g = 1.f / (1.f + __expf(-(acc[ni][r] + bs)));
      gate_out[n * 128 + colf] = g;
      float px = (float)cat[n * 256 + colf];
      float pz = (float)cat[n * 256 + 128 + colf];
      fl[(mo + lq * 4 + r) * 132 + colf] = (__bf16)(g * pz + (1.f - g) * px);
    }
  }
  __syncthreads();
  // phase2: Y1 = fl @ th1w  (K=128), wave tile 16n x 128f2
  int hm2 = wv >> 1, f128 = (wv & 1) * 128;
  f32x4 acc2[8] = {};
  for (int k0 = 0; k0 < 128; k0 += 32) {
    bf16x8 a = *(const bf16x8*)(fl + (hm2 * 16 + lr) * 132 + k0 + lq * 8);
    #pragma unroll
    for (int ni = 0; ni < 8; ++ni) {
      bf16x8 b = *(const bf16x8*)(th1w + (long)(f128 + ni * 16 + lr) * 128 + k0 + lq * 8);
      acc2[ni] = mfma16(a, b, acc2[ni]);
    }
  }
  int lanep = (hm2 * 2 + (lq >> 1)) * 16 + lr;
  #pragma unroll
  for (int ni = 0; ni < 8; ++ni) {
    int fblk = (f128 >> 4) + ni;
    bf16x4 pk;
    #pragma unroll
    for (int r = 0; r < 4; ++r) {
      long n = n0 + hm2 * 16 + lq * 4 + r;
      pk[r] = (__bf16)(acc2[ni][r] * isd[n]);
    }
    *(bf16x4*)(Yf + (((long)fblk * 640 + blockIdx.x) * 64 + lanep) * 8 + (lq & 1) * 4) = pk;
  }
}

// --------------------------------------------- He partials: fragment-major
__global__ __launch_bounds__(512) void at_gemm_kern(const bf16_t* __restrict__ Hbp,
                                                    const bf16_t* __restrict__ Yf,
                                                    bf16_t* __restrict__ part) {
  __shared__ bf16_t T[128 * 72];       // [e_local][64 n + pad]
  int t = threadIdx.x, l = t & 63, wv = t >> 6;
  int lr = l & 15, lq = l >> 4;
  int eh = wv >> 2, fq = wv & 3;
  int e0 = blockIdx.x * 128;
  int s0 = blockIdx.y * 20, s1 = s0 + 20;
  int rp = t >> 4;
  int ck = t & 15;
  f32x4 acc[4][4] = {};
  const bf16_t* src = Hbp + (((long)(e0 >> 6) + (ck >> 3)) * NNP + (long)s0 * 64 + 2 * rp) * 64
                          + (ck & 7) * 8;
  bf16x8 ra = *(const bf16x8*)src;
  bf16x8 rb = *(const bf16x8*)(src + 64);
  for (int s = s0; s < s1; ++s) {
    __syncthreads();
    #pragma unroll
    for (int j = 0; j < 8; ++j) {
      int jj = (j + ck) & 7;
      int el = ck * 8 + jj;
      unsigned lo = (unsigned)__builtin_bit_cast(unsigned short, (__bf16)ra[jj]);
      unsigned hi = (unsigned)__builtin_bit_cast(unsigned short, (__bf16)rb[jj]);
      *(unsigned*)(T + el * 72 + rp * 2) = lo | (hi << 16);
    }
    __syncthreads();
    if (s + 1 < s1) {
      src += 64 * 64;
      ra = *(const bf16x8*)src;
      rb = *(const bf16x8*)(src + 64);
    }
    #pragma unroll
    for (int k32 = 0; k32 < 2; ++k32) {
      bf16x8 a[4], b[4];
      #pragma unroll
      for (int ni = 0; ni < 4; ++ni)
        a[ni] = *(const bf16x8*)(T + (eh * 64 + ni * 16 + lr) * 72 + k32 * 32 + lq * 8);
      const bf16_t* bp = Yf + ((long)(s * 2 + k32) * 64 + l) * 8;
      #pragma unroll
      for (int ni = 0; ni < 4; ++ni)
        b[ni] = *(const bf16x8*)(bp + (long)(fq * 4 + ni) * 640 * 512);
      #pragma unroll
      for (int ae = 0; ae < 4; ++ae)
        #pragma unroll
        for (int bf = 0; bf < 4; ++bf)
          acc[ae][bf] = mfma16(a[ae], b[bf], acc[ae][bf]);
    }
  }
  bf16_t* pp = part + (long)blockIdx.y * (256 * 4096);
  #pragma unroll
  for (int ae = 0; ae < 4; ++ae) {
    int eblk16 = (e0 >> 4) + eh * 4 + ae;
    #pragma unroll
    for (int bf = 0; bf < 4; ++bf) {
      int fblk = fq * 4 + bf;
      f32x4 v = acc[ae][bf];
      bf16x4 pk;
      for (int r = 0; r < 4; ++r) pk[r] = (__bf16)v[r];
      *(bf16x4*)(pp + (((long)eblk16 * 16 + fblk) * 64 + l) * 4) = pk;
    }
  }
}

// Hef[f][e] (fragment-major) = es[e] * sum_s part[s][...]
__global__ __launch_bounds__(256) void reduce_he(const bf16_t* __restrict__ part,
                                                 const float* __restrict__ es,
                                                 bf16_t* __restrict__ Hef) {
  int u = blockIdx.x * 256 + threadIdx.x;
  int lane = u & 63, tile = u >> 6;
  int fblk = tile & 15, eblk16 = tile >> 4;
  int lr = lane & 15, lq = lane >> 4;
  int e_base = eblk16 * 16 + lq * 4;
  float a0 = 0.f, a1 = 0.f, a2 = 0.f, a3 = 0.f;
  #pragma unroll
  for (int s = 0; s < AT_S; ++s) {
    bf16x4 v = *(const bf16x4*)(part + (long)s * (256 * 4096) + (long)u * 4);
    a0 += (float)v[0]; a1 += (float)v[1]; a2 += (float)v[2]; a3 += (float)v[3];
  }
  f32x4 e4 = *(const f32x4*)(es + e_base);
  bf16x4 pk;
  pk[0] = (__bf16)(a0 * e4[0]); pk[1] = (__bf16)(a1 * e4[1]);
  pk[2] = (__bf16)(a2 * e4[2]); pk[3] = (__bf16)(a3 * e4[3]);
  int eblk32 = eblk16 >> 1;
  int lanep = ((eblk16 & 1) * 2 + (lq >> 1)) * 16 + lr;
  long slot = (((long)fblk * 128 + eblk32) * 64 + lanep) * 8 + (lq & 1) * 4;
  *(bf16x4*)(Hef + slot) = pk;
}

// -------- conv out: h[n][f] = relu(isd[n]*(Hbp[n]@He) + bias) -------------
// CONV=1: fuse Y2 = h@th2*isd (h stays in LDS, never hits HBM).
// CONV=2: fuse logits = h@out_w + out_b.
template<int CONV>
__global__ __launch_bounds__(512) void out_gemm_kern(const bf16_t* __restrict__ Hef,
                                                     const bf16_t* __restrict__ Hbp,
                                                     const float* __restrict__ isd,
                                                     const float* __restrict__ bias,
                                                     const bf16_t* __restrict__ th2w,
                                                     bf16_t* __restrict__ Yf,
                                                     const float* __restrict__ ow,
                                                     const float* __restrict__ ob,
                                                     float* __restrict__ out) {
  __shared__ bf16_t lbuf[2][4096];     // [buf][frag 8][lane 64][8]
  __shared__ float lgp[8][64][2];      // CONV2 logits partials
  __shared__ bf16_t hl[64 * 260];      // CONV1 h tile, stride 260 bf16
  int t = threadIdx.x, l = t & 63, wv = t >> 6;
  int lr = l & 15, lq = l >> 4;
  long r0 = (long)blockIdx.x * 64;
  f32x4 acc[4][2] = {};
  const bf16_t* asrc = Hbp + (r0 + (wv >> 1) * 16 + lr) * 64 + (wv & 1) * 32 + lq * 8;
  const bf16_t* bbase = Hef + (long)l * 8;
  bf16x8 rg = *(const bf16x8*)asrc;
  int c = 0;
  for (int s = 0; s < 64; ++s) {
    *(bf16x8*)(&lbuf[c][wv * 512 + l * 8]) = rg;
    __syncthreads();
    if (s + 1 < 64) rg = *(const bf16x8*)(asrc + (long)(s + 1) * NNP * 64);
    #pragma unroll
    for (int k32 = 0; k32 < 2; ++k32) {
      bf16x8 a[4], b[2];
      #pragma unroll
      for (int mi = 0; mi < 4; ++mi)
        a[mi] = *(const bf16x8*)(&lbuf[c][(mi * 2 + k32) * 512 + l * 8]);
      int eblk = s * 2 + k32;
      #pragma unroll
      for (int ni = 0; ni < 2; ++ni)
        b[ni] = *(const bf16x8*)(bbase + ((long)(wv * 2 + ni) * 128 + eblk) * 512);
      #pragma unroll
      for (int mi = 0; mi < 4; ++mi) {
        acc[mi][0] = mfma16(a[mi], b[0], acc[mi][0]);
        acc[mi][1] = mfma16(a[mi], b[1], acc[mi][1]);
      }
    }
    c ^= 1;
  }
  #pragma unroll
  for (int mi = 0; mi < 4; ++mi) {
    long nb = r0 + mi * 16 + lq * 4;
    #pragma unroll
    for (int r = 0; r < 4; ++r) {
      long n = nb + r;
      float sd = (n < NN) ? isd[n] : 0.f;
      float a0 = 0.f, a1 = 0.f;
      #pragma unroll
      for (int ni = 0; ni < 2; ++ni) {
        int f = wv * 32 + ni * 16 + lr;
        float vv = acc[mi][ni][r] * sd + bias[f];
        vv = vv > 0.f ? vv : 0.f;
        if constexpr (CONV == 1) {
          hl[(mi * 16 + lq * 4 + r) * 260 + f] = (__bf16)vv;   // pad rows masked later
        } else {
          a0 += vv * ow[f * 2];
          a1 += vv * ow[f * 2 + 1];
        }
      }
      if constexpr (CONV == 2) {
        #pragma unroll
        for (int m = 1; m < 16; m <<= 1) { a0 += __shfl_xor(a0, m); a1 += __shfl_xor(a1, m); }
        if (lr == 0) {
          int rowl = mi * 16 + lq * 4 + r;
          lgp[wv][rowl][0] = a0;
          lgp[wv][rowl][1] = a1;
        }
      }
    }
  }
  if constexpr (CONV == 1) {
    __syncthreads();
    // phase2: Y2[64n][256f2] = hl @ th2w (K=256), *isd, EPI_Y fragment store
    int nh = wv >> 2, fq = wv & 3;
    f32x4 acc2[2][4] = {};
    for (int k0 = 0; k0 < 256; k0 += 32) {
      bf16x8 a0v = *(const bf16x8*)(hl + (nh * 32 + lr) * 260 + k0 + lq * 8);
      bf16x8 a1v = *(const bf16x8*)(hl + (nh * 32 + 16 + lr) * 260 + k0 + lq * 8);
      #pragma unroll
      for (int ni = 0; ni < 4; ++ni) {
        bf16x8 b = *(const bf16x8*)(th2w + (long)(fq * 64 + ni * 16 + lr) * 256 + k0 + lq * 8);
        acc2[0][ni] = mfma16(a0v, b, acc2[0][ni]);
        acc2[1][ni] = mfma16(a1v, b, acc2[1][ni]);
      }
    }
    long nblk = blockIdx.x * 2 + nh;
    #pragma unroll
    for (int mi = 0; mi < 2; ++mi) {
      int lanep = (mi * 2 + (lq >> 1)) * 16 + lr;
      #pragma unroll
      for (int ni = 0; ni < 4; ++ni) {
        int fblk = fq * 4 + ni;
        bf16x4 pk;
        #pragma unroll
        for (int r = 0; r < 4; ++r) {
          long n = r0 + nh * 32 + mi * 16 + lq * 4 + r;
          float sc = (n < NN) ? isd[n] : 0.f;
          pk[r] = (__bf16)(acc2[mi][ni][r] * sc);
        }
        *(bf16x4*)(Yf + (((long)fblk * 640 + nblk) * 64 + lanep) * 8 + (lq & 1) * 4) = pk;
      }
    }
  } else {
    __syncthreads();
    if (t < 64) {
      float s0 = 0.f, s1 = 0.f;
      #pragma unroll
      for (int wvi = 0; wvi < 8; ++wvi) { s0 += lgp[wvi][t][0]; s1 += lgp[wvi][t][1]; }
      long n = r0 + t;
      if (n < NN) {
        out[n * 2]     = s0 + ob[0];
        out[n * 2 + 1] = s1 + ob[1];
      }
    }
  }
}

// ============================================================== launcher
extern "C" void kernel_launch(void* const* d_in, const int* in_sizes, int n_in,
                              void* d_out, int out_size, void* d_ws, size_t ws_size,
                              hipStream_t stream) {
  const float* x    = (const float*)d_in[0];
  const float* z    = (const float*)d_in[1];
  const float* H    = (const float*)d_in[2];
  const float* w    = (const float*)d_in[3];
  const float* psi_w = (const float*)d_in[4];
  const float* psi_b = (const float*)d_in[5];
  const float* phi_w = (const float*)d_in[6];
  const float* phi_b = (const float*)d_in[7];
  const float* g1_w  = (const float*)d_in[8];
  const float* g1_b  = (const float*)d_in[9];
  const float* g2_w  = (const float*)d_in[10];
  const float* g2_b  = (const float*)d_in[11];
  const float* th1   = (const float*)d_in[12];
  const float* b1    = (const float*)d_in[13];
  const float* th2   = (const float*)d_in[14];
  const float* b2    = (const float*)d_in[15];
  const float* out_w = (const float*)d_in[16];
  const float* out_b = (const float*)d_in[17];

  float* logits_out = (float*)d_out;                 // [20000][2]
  float* gate_out   = logits_out + (size_t)NN * 2;   // [20000][128]

  char* p = (char*)d_ws;
  auto alloc = [&](size_t bytes) { char* r = p; p += (bytes + 255) & ~(size_t)255; return r; };
  float* Dvp  = (float*)alloc((size_t)NEB * NNP * 4);
  float* Dep  = (float*)alloc((size_t)NNB * NE * 4);
  float* isd  = (float*)alloc((size_t)NN * 4);
  float* es   = (float*)alloc((size_t)NE * 4);
  bf16_t* cat   = (bf16_t*)alloc((size_t)NN * 256 * 2);
  bf16_t* hid1  = (bf16_t*)alloc((size_t)NN * 256 * 2);
  bf16_t* Yf    = (bf16_t*)alloc((size_t)16 * 640 * 512 * 2);   // 10.49 MB
  bf16_t* Hef   = (bf16_t*)alloc((size_t)16 * 128 * 512 * 2);   // 2.1 MB
  bf16_t* pbuf  = (bf16_t*)alloc((size_t)AT_S * 256 * 4096 * 2); // 33.5 MB
  bf16_t* Hbp   = (bf16_t*)alloc((size_t)NNP * NE * 2);          // 168 MB
  bf16_t* psi_wt = (bf16_t*)alloc(65536 * 2);
  bf16_t* phi_wt = (bf16_t*)alloc(32768 * 2);
  bf16_t* g1_wt  = (bf16_t*)alloc(65536 * 2);
  bf16_t* g2_wt  = (bf16_t*)alloc(32768 * 2);
  bf16_t* th1_wt = (bf16_t*)alloc(32768 * 2);
  bf16_t* th2_wt = (bf16_t*)alloc(65536 * 2);

  cvtw_kern<<<1152, 256, 0, stream>>>(psi_w, phi_w, g1_w, g2_w, th1, th2,
                                      psi_wt, phi_wt, g1_wt, g2_wt, th1_wt, th2_wt);
  stats_cvt_kern<<<dim3(NEB, NNB), 256, 0, stream>>>(H, w, Dvp, Dep, Hbp);
  finalize_kern<<<79, 256, 0, stream>>>(Dvp, Dep, w, isd, es);

  // front-end MLP chain
  gemm_node_kern<true,  EPI_CAT ><<<dim3(625, 1), 256, 0, stream>>>(x, 512, psi_wt, 512, psi_b, cat,       256);
  gemm_node_kern<true,  EPI_CAT ><<<dim3(625, 1), 256, 0, stream>>>(z, 256, phi_wt, 256, phi_b, cat + 128, 256);
  gemm_node_kern<false, EPI_RELU><<<dim3(625, 2), 256, 0, stream>>>(cat, 256, g1_wt, 256, g1_b, hid1, 256);
  gate_y_kern<<<640, 256, 0, stream>>>(hid1, g2_wt, g2_b, cat, th1_wt, isd, gate_out, Yf);

  // hconv 1 (+ fused Y2 producer)
  at_gemm_kern<<<dim3(32, AT_S), 512, 0, stream>>>(Hbp, Yf, pbuf);
  reduce_he<<<1024, 256, 0, stream>>>(pbuf, es, Hef);
  out_gemm_kern<1><<<320, 512, 0, stream>>>(Hef, Hbp, isd, b1, th2_wt, Yf,
                                            nullptr, nullptr, nullptr);

  // hconv 2 (+ fused logits)
  at_gemm_kern<<<dim3(32, AT_S), 512, 0, stream>>>(Hbp, Yf, pbuf);
  reduce_he<<<1024, 256, 0, stream>>>(pbuf, es, Hef);
  out_gemm_kern<2><<<320, 512, 0, stream>>>(Hef, Hbp, isd, b2, nullptr, nullptr,
                                            out_w, out_b, logits_out);

  (void)in_sizes; (void)n_in; (void)out_size; (void)ws_size;
}